// Round 3
// baseline (376.249 us; speedup 1.0000x reference)
//
#include <hip/hip_runtime.h>

#define B_SZ 8
#define N_SZ 4096
#define M_SZ 2048
#define D_SZ 512

typedef __attribute__((ext_vector_type(8))) short bf16x8;
typedef __attribute__((ext_vector_type(4))) float f32x4;
typedef __attribute__((address_space(1))) const void* gptr1;
typedef __attribute__((address_space(3))) void* lptr3;

__device__ __forceinline__ unsigned short f2bf(float x) {
    unsigned int u = __builtin_bit_cast(unsigned int, x);
    u += 0x7fffu + ((u >> 16) & 1u);
    return (unsigned short)(u >> 16);
}
__device__ __forceinline__ float bf2f(unsigned short u) {
    unsigned int x = ((unsigned int)u) << 16;
    return __builtin_bit_cast(float, x);
}

__device__ __forceinline__ void vmcnt0() { asm volatile("s_waitcnt vmcnt(0)" ::: "memory"); }
__device__ __forceinline__ void vmcnt2() { asm volatile("s_waitcnt vmcnt(2)" ::: "memory"); }

// ---------- old 128x128 B^T GEMM mainloop (kept for gemm1) ----------
__device__ __forceinline__ void bt_mainloop(
    const unsigned short* __restrict__ A, const unsigned short* __restrict__ Bt,
    int lda, int ldb, int rowBase, int colBase, int K,
    unsigned short* As, unsigned short* Bs, f32x4 acc[4][4])
{
    const int tid  = threadIdx.x;
    const int lane = tid & 63;
    const int w    = tid >> 6;
    const int wr   = (w >> 1) * 64;
    const int wc   = (w & 1) * 64;
    const int lr   = lane & 15;
    const int kq   = lane >> 4;

    const int srow0 = w * 16 + (lane >> 2);
    const int skk   = (lane & 3) * 8;

    for (int k0 = 0; k0 < K; k0 += 32) {
#pragma unroll
        for (int j = 0; j < 2; ++j) {
            const unsigned short* ga = A  + (size_t)(rowBase + srow0 + j * 64) * lda + (k0 + skk);
            const unsigned short* gb = Bt + (size_t)(colBase + srow0 + j * 64) * ldb + (k0 + skk);
            __builtin_amdgcn_global_load_lds((gptr1)ga, (lptr3)(As + (j * 4 + w) * 512), 16, 0, 0);
            __builtin_amdgcn_global_load_lds((gptr1)gb, (lptr3)(Bs + (j * 4 + w) * 512), 16, 0, 0);
        }
        asm volatile("s_waitcnt vmcnt(0)" ::: "memory");
        __syncthreads();

        bf16x8 af[4], bq[4];
#pragma unroll
        for (int i = 0; i < 4; ++i) {
            af[i] = *(const bf16x8*)(As + (wr + i * 16 + lr) * 32 + kq * 8);
            bq[i] = *(const bf16x8*)(Bs + (wc + i * 16 + lr) * 32 + kq * 8);
        }
#pragma unroll
        for (int mi = 0; mi < 4; ++mi)
#pragma unroll
            for (int ni = 0; ni < 4; ++ni)
                acc[mi][ni] = __builtin_amdgcn_mfma_f32_16x16x32_bf16(af[mi], bq[ni], acc[mi][ni], 0, 0, 0);
        __syncthreads();
    }
}

// ---------- 4-phase 256-wide mainloop machinery ----------
// Stage one half-tile (NROWS x 64 k-elems, bf16) global -> LDS, with the k-slot
// XOR swizzle applied on the GLOBAL side (global_load_lds dest must be linear).
// LDS layout: row-major [NROWS][64] bf16 (128 B rows); 16B slot s of row r holds
// global k-slot s ^ (r & 7).
template<int NROWS>
__device__ __forceinline__ void stage_half(
    const unsigned short* __restrict__ G, int ld, int grow0, int k0,
    unsigned short* lds, int tid)
{
    const int w = tid >> 6, l = tid & 63;
#pragma unroll
    for (int c = 0; c < NROWS / 64; ++c) {
        const int idx  = (c * 8 + w) * 64 + l;      // 0 .. NROWS*8-1
        const int row  = idx >> 3;                  // local row
        const int slot = (idx & 7) ^ (row & 7);     // pre-swizzled global k-slot
        const unsigned short* ga = G + (size_t)(grow0 + row) * ld + (k0 + slot * 8);
        __builtin_amdgcn_global_load_lds((gptr1)ga, (lptr3)(lds + (c * 8 + w) * 512), 16, 0, 0);
    }
}

// One merged phase: read af for A-half QM once, bq for ALL n-frags (both B
// halves), then 32 (BN=256) / 16 (BN=128) MFMAs. This halves LDS re-reads vs
// the 8-phase (QM,QN) split: 16 reads per 32 MFMA instead of 24.
//   A row = QM*128 + (w>>2)*64 + mi*16 + lr
//   B row = (nj/(NF/2))*(BN/2) + (w&3)*(BN/8) + (nj%(NF/2))*16 + lr
#define PHASE4(BUF, QM, STAGES, TAIL)                                                 \
  {                                                                                   \
    const unsigned short* Ab = As + (BUF) * (256 * 64);                               \
    const unsigned short* Bb = Bs + (BUF) * (BN * 64);                                \
    bf16x8 af[4][2], bq[NF][2];                                                       \
    _Pragma("unroll") for (int nj = 0; nj < NF; ++nj)                                 \
      _Pragma("unroll") for (int ks = 0; ks < 2; ++ks) {                              \
        const int row = (nj / (NF / 2)) * (BN / 2) + wcol + (nj % (NF / 2)) * 16 + lr; \
        bq[nj][ks] = *(const bf16x8*)(Bb + row * 64 + (((ks * 4 + kq) ^ (row & 7)) * 8)); \
      }                                                                               \
    _Pragma("unroll") for (int mi = 0; mi < 4; ++mi)                                  \
      _Pragma("unroll") for (int ks = 0; ks < 2; ++ks) {                              \
        const int row = (QM) * 128 + wrow + mi * 16 + lr;                             \
        af[mi][ks] = *(const bf16x8*)(Ab + row * 64 + (((ks * 4 + kq) ^ (row & 7)) * 8)); \
      }                                                                               \
    STAGES;                                                                           \
    __builtin_amdgcn_s_barrier();                                                     \
    __builtin_amdgcn_s_setprio(1);                                                    \
    _Pragma("unroll") for (int mi = 0; mi < 4; ++mi)                                  \
      _Pragma("unroll") for (int nj = 0; nj < NF; ++nj)                               \
        _Pragma("unroll") for (int ks = 0; ks < 2; ++ks)                              \
          acc[(QM) * 4 + mi][nj] = __builtin_amdgcn_mfma_f32_16x16x32_bf16(           \
              af[mi][ks], bq[nj][ks], acc[(QM) * 4 + mi][nj], 0, 0, 0);               \
    __builtin_amdgcn_s_setprio(0);                                                    \
    TAIL;                                                                             \
    __builtin_amdgcn_s_barrier();                                                     \
  }

// C[rowBase:+256, colBase:+BN] += A[256 x K] * Bt[BN x K]^T, 512 threads / 8 waves.
// 4 phases per iteration (2 K-tiles of 64). Race-free stage ring — every stage
// lands after a barrier following its region's last-reading phase:
//   M1 (buf0,QM0; reads A0,B0,B1): stage b1.{A1,B0,B1}   (read last in prior M4)
//   M2 (buf0,QM1; reads A1,B0,B1): stage b0'.A0 (A0 read M1) + vmcnt(2) -> buf1 ready
//   M3 (buf1,QM0):                 stage b0'.{A1,B0,B1}  (read last M2)
//   M4 (buf1,QM1):                 stage b1'.A0 (A0 read M3) + vmcnt(2) -> b0' ready
// Per-thread loads: A-half=2, B-half=2 (BN=256) or 1 (BN=128). At M2/M4 tail the
// oldest outstanding loads are exactly the buffer being certified; vmcnt(2)
// leaves only the just-issued next A0 in flight. Gaps issue->use >= 2 phases.
template<int BN>
__device__ __forceinline__ void mainloop4(
    const unsigned short* __restrict__ A, const unsigned short* __restrict__ Bt,
    int lda, int ldb, int rowBase, int colBase, int K,
    unsigned short* As, unsigned short* Bs, f32x4 (&acc)[8][BN / 64])
{
    constexpr int NF   = BN / 64;       // n-frags per phase (4 or 2)
    constexpr int BNH  = BN / 2;
    constexpr int ABUF = 256 * 64, AH = 128 * 64;
    constexpr int BBUF = BN * 64,  BH = BNH * 64;
    const int tid = threadIdx.x, lane = tid & 63, w = tid >> 6;
    const int wrow = (w >> 2) * 64;
    const int wcol = (w & 3) * (BN / 8);
    const int lr = lane & 15, kq = lane >> 4;
    const int niter = K >> 7;

    // prologue: buf0 all 4 halves + buf1.A0 in flight
    stage_half<128>(A,  lda, rowBase,       0,  As,        tid);
    stage_half<128>(A,  lda, rowBase + 128, 0,  As + AH,   tid);
    stage_half<BNH>(Bt, ldb, colBase,       0,  Bs,        tid);
    stage_half<BNH>(Bt, ldb, colBase + BNH, 0,  Bs + BH,   tid);
    stage_half<128>(A,  lda, rowBase,       64, As + ABUF, tid);
    vmcnt2();
    __builtin_amdgcn_s_barrier();

    for (int I = 0; I < niter; ++I) {
        const bool nl = (I + 1 < niter);
        const int ke = I << 7;
        PHASE4(0, 0,
          { stage_half<128>(A,  lda, rowBase + 128, ke + 64, As + ABUF + AH, tid);
            stage_half<BNH>(Bt, ldb, colBase,       ke + 64, Bs + BBUF,      tid);
            stage_half<BNH>(Bt, ldb, colBase + BNH, ke + 64, Bs + BBUF + BH, tid); },
          {});
        PHASE4(0, 1,
          { if (nl) stage_half<128>(A, lda, rowBase, ke + 128, As, tid); },
          { if (nl) vmcnt2(); else vmcnt0(); });
        PHASE4(1, 0,
          { if (nl) { stage_half<128>(A,  lda, rowBase + 128, ke + 128, As + AH, tid);
                      stage_half<BNH>(Bt, ldb, colBase,       ke + 128, Bs,      tid);
                      stage_half<BNH>(Bt, ldb, colBase + BNH, ke + 128, Bs + BH, tid); } },
          {});
        PHASE4(1, 1,
          { if (nl) stage_half<128>(A, lda, rowBase, ke + 192, As + ABUF, tid); },
          { if (nl) vmcnt2(); });
    }
}

// ---------- prep: normalize text[1] rows -> tn, copy t1 into out, zero L & SS ----------
__global__ __launch_bounds__(256) void prep_tn_k(
    const float* __restrict__ text, unsigned short* __restrict__ tn,
    float* __restrict__ out, float* __restrict__ L, float* __restrict__ SS)
{
    const int m = blockIdx.x;
    const int t = threadIdx.x;  // 256
    const float* t1 = text + (size_t)M_SZ * D_SZ;
    float2 v = ((const float2*)(t1 + (size_t)m * D_SZ))[t];
    float s = v.x * v.x + v.y * v.y;
#pragma unroll
    for (int off = 32; off > 0; off >>= 1) s += __shfl_down(s, off);
    __shared__ float partial[4];
    if ((t & 63) == 0) partial[t >> 6] = s;
    __syncthreads();
    float norm = sqrtf(partial[0] + partial[1] + partial[2] + partial[3]);
    norm = fmaxf(norm, 1e-8f);
    const float inv = 1.f / norm;
    ushort2 pk; pk.x = f2bf(v.x * inv); pk.y = f2bf(v.y * inv);
    ((ushort2*)(tn + (size_t)m * D_SZ))[t] = pk;
#pragma unroll
    for (int b = 0; b < B_SZ; ++b)
        ((float2*)(out + ((size_t)(b * M_SZ + m)) * (2 * D_SZ) + D_SZ))[t] = v;
    if (m < 64) L[m * 256 + t] = 0.f;
    if (m < 128) SS[m * 256 + t] = 0.f;
}

// ---------- prep: transpose W (fp32 [d][e]) -> Wt (bf16 [e][d]) ----------
__global__ __launch_bounds__(256) void prep_w_k(
    const float* __restrict__ W, unsigned short* __restrict__ Wt)
{
    const int dt = blockIdx.x, et = blockIdx.y;
    const int t = threadIdx.x;
    __shared__ unsigned short tile[64][72];
    const int rr = t >> 4;
    const int cc = (t & 15) * 4;
#pragma unroll
    for (int p = 0; p < 4; ++p) {
        const int d = p * 16 + rr;
        const float4 v = *(const float4*)(W + (size_t)(dt * 64 + d) * D_SZ + et * 64 + cc);
        tile[d][cc] = f2bf(v.x); tile[d][cc + 1] = f2bf(v.y);
        tile[d][cc + 2] = f2bf(v.z); tile[d][cc + 3] = f2bf(v.w);
    }
    __syncthreads();
#pragma unroll
    for (int p = 0; p < 4; ++p) {
        const int e = p * 16 + rr;
        ushort4 pk;
        pk.x = tile[cc][e]; pk.y = tile[cc + 1][e]; pk.z = tile[cc + 2][e]; pk.w = tile[cc + 3][e];
        *(ushort4*)(Wt + (size_t)(et * 64 + e) * D_SZ + dt * 64 + cc) = pk;
    }
}

// ---------- features fp32 -> V bf16 [b*n][d] and Vt bf16 [b][d][n] ----------
__global__ __launch_bounds__(256) void convert_feat_k(
    const float* __restrict__ feat, unsigned short* __restrict__ V,
    unsigned short* __restrict__ Vt)
{
    const int nt = blockIdx.x, dt = blockIdx.y, b = blockIdx.z;
    const int t = threadIdx.x;
    __shared__ unsigned short tile[64][72];
    const int rr = t >> 4;
    const int cc = (t & 15) * 4;
#pragma unroll
    for (int p = 0; p < 4; ++p) {
        const int r = p * 16 + rr;
        const size_t grow = (size_t)(b * N_SZ + nt * 64 + r);
        const float4 v = *(const float4*)(feat + grow * D_SZ + dt * 64 + cc);
        ushort4 pk; pk.x = f2bf(v.x); pk.y = f2bf(v.y); pk.z = f2bf(v.z); pk.w = f2bf(v.w);
        *(ushort4*)(V + grow * D_SZ + dt * 64 + cc) = pk;
        tile[r][cc] = pk.x; tile[r][cc + 1] = pk.y; tile[r][cc + 2] = pk.z; tile[r][cc + 3] = pk.w;
    }
    __syncthreads();
#pragma unroll
    for (int p = 0; p < 4; ++p) {
        const int d = p * 16 + rr;
        ushort4 pk;
        pk.x = tile[cc][d]; pk.y = tile[cc + 1][d]; pk.z = tile[cc + 2][d]; pk.w = tile[cc + 3][d];
        *(ushort4*)(Vt + ((size_t)(b * D_SZ + dt * 64 + d)) * N_SZ + nt * 64 + cc) = pk;
    }
}

// ---------- gemm1: f1b = bf16(V @ Wt^T + bias); SS[row] += sum(f1^2) ----------
__global__ __launch_bounds__(256) void gemm1_k(
    const unsigned short* __restrict__ V, const unsigned short* __restrict__ Wt,
    const float* __restrict__ bias, unsigned short* __restrict__ f1b,
    float* __restrict__ SS)
{
    __shared__ unsigned short As[128 * 32];
    __shared__ unsigned short Bs[128 * 32];
    f32x4 acc[4][4];
#pragma unroll
    for (int i = 0; i < 4; ++i)
#pragma unroll
        for (int j = 0; j < 4; ++j) acc[i][j] = (f32x4){0.f, 0.f, 0.f, 0.f};
    const int tid = threadIdx.x, lane = tid & 63, w = tid >> 6;
    const int wr = (w >> 1) * 64, wc = (w & 1) * 64, lr = lane & 15, kq = lane >> 4;

    const int rowBase = blockIdx.x * 128;
    const int colBase = blockIdx.y * 128;
    bt_mainloop(V, Wt, D_SZ, D_SZ, rowBase, colBase, D_SZ, As, Bs, acc);

#pragma unroll
    for (int mi = 0; mi < 4; ++mi) {
        const int r0 = rowBase + wr + mi * 16 + kq * 4;
        float s[4] = {0.f, 0.f, 0.f, 0.f};
#pragma unroll
        for (int ni = 0; ni < 4; ++ni) {
            const int c = colBase + wc + ni * 16 + lr;
            const float bv = bias[c];
#pragma unroll
            for (int r = 0; r < 4; ++r) {
                const float v = acc[mi][ni][r] + bv;
                f1b[(size_t)(r0 + r) * D_SZ + c] = f2bf(v);
                s[r] += v * v;
            }
        }
#pragma unroll
        for (int off = 1; off <= 8; off <<= 1)
#pragma unroll
            for (int r = 0; r < 4; ++r) s[r] += __shfl_xor(s[r], off);
        if (lr == 0) {
#pragma unroll
            for (int r = 0; r < 4; ++r) atomicAdd(&SS[r0 + r], s[r]);
        }
    }
}

// ---------- normalize: fn = bf16(f1b * rsqrt-ish(SS)) ----------
__global__ __launch_bounds__(128) void normalize_k(
    const unsigned short* __restrict__ f1b, const float* __restrict__ SS,
    unsigned short* __restrict__ fn)
{
    const int row = blockIdx.x;
    const int t = threadIdx.x;  // 128
    const float norm = fmaxf(sqrtf(SS[row]), 1e-8f);
    const float inv = 1.f / norm;
    ushort4 v = ((const ushort4*)(f1b + (size_t)row * D_SZ))[t];
    ushort4 o;
    o.x = f2bf(bf2f(v.x) * inv); o.y = f2bf(bf2f(v.y) * inv);
    o.z = f2bf(bf2f(v.z) * inv); o.w = f2bf(bf2f(v.w) * inv);
    ((ushort4*)(fn + (size_t)row * D_SZ))[t] = o;
}

// ---------- gemm2 (4-phase 256x256): sim = fn @ tn^T; E[b][m][n]=bf16(exp); L += sums ----------
__global__ __launch_bounds__(512, 1) void gemm2_k8(
    const unsigned short* __restrict__ fn, const unsigned short* __restrict__ tn,
    unsigned short* __restrict__ E, float* __restrict__ L)
{
    __shared__ unsigned short smem[65536];   // 128 KiB: staging; reused as swizzled P-tile
    unsigned short* As = smem;               // [2][256*64]
    unsigned short* Bs = smem + 32768;       // [2][256*64]
    f32x4 acc[8][4];
#pragma unroll
    for (int i = 0; i < 8; ++i)
#pragma unroll
        for (int j = 0; j < 4; ++j) acc[i][j] = (f32x4){0.f, 0.f, 0.f, 0.f};

    const int lin = blockIdx.x;              // 1024 blocks
    const int xcd = lin & 7, slot = lin >> 3;
    const int mt = slot & 7;                 // tn col-tile (inner: tn L2-resident)
    const int rt = (slot >> 3) * 8 + xcd;    // fn row-tile pinned per XCD
    const int rowBase = rt * 256;            // fn rows (b*4096 + n)
    const int colBase = mt * 256;            // tn rows (m)

    mainloop4<256>(fn, tn, D_SZ, D_SZ, rowBase, colBase, D_SZ, As, Bs, acc);
    __syncthreads();                         // mainloop drained (last iter vmcnt(0))

    const int tid = threadIdx.x, lane = tid & 63, w = tid >> 6;
    const int wrow = (w >> 2) * 64, wcol = (w & 3) * 32;
    const int lr = lane & 15, kq = lane >> 4;
    const int b = rowBase >> 12;
    const int nb0 = rowBase & 4095;

    // write exp() into swizzled P[m 256][n 256] (16B slot s of row m at s^(m&7))
    unsigned short* P = smem;
    float ps[4] = {0.f, 0.f, 0.f, 0.f};
#pragma unroll
    for (int a = 0; a < 8; ++a) {
        const int n0 = (a >> 2) * 128 + wrow + (a & 3) * 16 + kq * 4;   // local n
#pragma unroll
        for (int j = 0; j < 4; ++j) {
            const int m = (j >> 1) * 128 + wcol + (j & 1) * 16 + lr;    // local m
            const float e0 = __expf(acc[a][j][0]);
            const float e1 = __expf(acc[a][j][1]);
            const float e2 = __expf(acc[a][j][2]);
            const float e3 = __expf(acc[a][j][3]);
            ushort4 pk; pk.x = f2bf(e0); pk.y = f2bf(e1); pk.z = f2bf(e2); pk.w = f2bf(e3);
            *(ushort4*)(P + m * 256 + (((n0 >> 3) ^ (m & 7)) * 8) + (n0 & 7)) = pk;
            ps[j] += (e0 + e1) + (e2 + e3);
        }
    }
#pragma unroll
    for (int j = 0; j < 4; ++j) {
        float p = ps[j];
        p += __shfl_down(p, 16);
        p += __shfl_down(p, 32);
        const int m = (j >> 1) * 128 + wcol + (j & 1) * 16 + lr;
        if (lane < 16) atomicAdd(&L[b * M_SZ + colBase + m], p);
    }
    __syncthreads();

    // coalesced transposed store: 32 lanes cover 512 contiguous bytes along n
    unsigned short* Eb = E + (size_t)b * M_SZ * N_SZ;
#pragma unroll
    for (int c = 0; c < 16; ++c) {
        const int rm = c * 16 + (tid >> 5);
        const int ns = tid & 31;
        bf16x8 v = *(const bf16x8*)(P + rm * 256 + ((ns ^ (rm & 7)) * 8));
        *(bf16x8*)(Eb + (size_t)(colBase + rm) * N_SZ + nb0 + ns * 8) = v;
    }
}

// ---------- gemm3 (4-phase 256x128): fm = (E @ Vt^T) / L -> out left half ----------
__global__ __launch_bounds__(512, 1) void gemm3_k8(
    const unsigned short* __restrict__ E, const unsigned short* __restrict__ Vt,
    const float* __restrict__ L, float* __restrict__ out)
{
    __shared__ unsigned short smem[49152];   // 96 KiB: As 64K + Bs 32K
    unsigned short* As = smem;               // [2][256*64]
    unsigned short* Bs = smem + 32768;       // [2][128*64]
    f32x4 acc[8][2];
#pragma unroll
    for (int i = 0; i < 8; ++i)
#pragma unroll
        for (int j = 0; j < 2; ++j) acc[i][j] = (f32x4){0.f, 0.f, 0.f, 0.f};

    const int lin = blockIdx.x;              // 256 blocks
    const int mtile = lin & 7;               // E m-tile pinned per XCD (2 MiB, L2-resident)
    const int slot = lin >> 3;
    const int dt = slot & 3;                 // Vt d-tile (inner)
    const int b = slot >> 2;
    const int rowBase = mtile * 256;         // m
    const int colBase = dt * 128;            // d

    const unsigned short* Ab = E + (size_t)b * M_SZ * N_SZ;
    const unsigned short* Bb = Vt + (size_t)b * D_SZ * N_SZ;
    mainloop4<128>(Ab, Bb, N_SZ, N_SZ, rowBase, colBase, N_SZ, As, Bs, acc);

    const int tid = threadIdx.x, lane = tid & 63, w = tid >> 6;
    const int wrow = (w >> 2) * 64, wcol = (w & 3) * 16;
    const int lr = lane & 15, kq = lane >> 4;

#pragma unroll
    for (int a = 0; a < 8; ++a) {
        const int r0 = rowBase + (a >> 2) * 128 + wrow + (a & 3) * 16 + kq * 4;
        float invl[4];
#pragma unroll
        for (int r = 0; r < 4; ++r) invl[r] = 1.f / L[b * M_SZ + r0 + r];
#pragma unroll
        for (int j = 0; j < 2; ++j) {
            const int d = colBase + j * 64 + wcol + lr;
#pragma unroll
            for (int r = 0; r < 4; ++r)
                out[((size_t)(b * M_SZ + r0 + r)) * (2 * D_SZ) + d] = acc[a][j][r] * invl[r];
        }
    }
}

extern "C" void kernel_launch(void* const* d_in, const int* in_sizes, int n_in,
                              void* d_out, int out_size, void* d_ws, size_t ws_size,
                              hipStream_t stream) {
    const float* features = (const float*)d_in[0];   // [8, 4096, 512]
    const float* text     = (const float*)d_in[1];   // [2, 2048, 512]
    const float* W        = (const float*)d_in[2];   // [512, 512]
    const float* bias     = (const float*)d_in[3];   // [512]
    float* out = (float*)d_out;                      // [8, 2048, 1024]
    char* ws = (char*)d_ws;

    // workspace layout (bytes)
    unsigned short* fn  = (unsigned short*)(ws + 0);            // 32 MiB
    unsigned short* tn  = (unsigned short*)(ws + 33554432);     //  2 MiB
    unsigned short* Wt  = (unsigned short*)(ws + 35651584);     // .5 MiB
    unsigned short* V   = (unsigned short*)(ws + 36175872);     // 32 MiB
    unsigned short* Vt  = (unsigned short*)(ws + 69730304);     // 32 MiB
    float*          L   = (float*)(ws + 103284736);             // 64 KiB
    float*          SS  = (float*)(ws + 103350272);             // 128 KiB
    unsigned short* E   = (unsigned short*)(ws + 103481344);    // 128 MiB
    unsigned short* f1b = (unsigned short*)(ws + 103481344);    // 32 MiB (aliases E; dead before gemm2)

    hipLaunchKernelGGL(prep_tn_k, dim3(M_SZ), dim3(256), 0, stream, text, tn, out, L, SS);
    hipLaunchKernelGGL(prep_w_k, dim3(8, 8), dim3(256), 0, stream, W, Wt);
    hipLaunchKernelGGL(convert_feat_k, dim3(64, 8, 8), dim3(256), 0, stream, features, V, Vt);
    hipLaunchKernelGGL(gemm1_k, dim3(256, 4), dim3(256), 0, stream, V, Wt, bias, f1b, SS);
    hipLaunchKernelGGL(normalize_k, dim3(32768), dim3(128), 0, stream, f1b, SS, fn);
    hipLaunchKernelGGL(gemm2_k8, dim3(1024), dim3(512), 0, stream, fn, tn, E, L);
    hipLaunchKernelGGL(gemm3_k8, dim3(256), dim3(512), 0, stream, E, Vt, L, out);
}

// Round 6
// 358.682 us; speedup vs baseline: 1.0490x; 1.0490x over previous
//
#include <hip/hip_runtime.h>

#define B_SZ 8
#define N_SZ 4096
#define M_SZ 2048
#define D_SZ 512

typedef __attribute__((ext_vector_type(8))) short bf16x8;
typedef __attribute__((ext_vector_type(4))) float f32x4;
typedef __attribute__((address_space(1))) const void* gptr1;
typedef __attribute__((address_space(3))) void* lptr3;

__device__ __forceinline__ unsigned short f2bf(float x) {
    unsigned int u = __builtin_bit_cast(unsigned int, x);
    u += 0x7fffu + ((u >> 16) & 1u);
    return (unsigned short)(u >> 16);
}
__device__ __forceinline__ float bf2f(unsigned short u) {
    unsigned int x = ((unsigned int)u) << 16;
    return __builtin_bit_cast(float, x);
}

__device__ __forceinline__ void vmcnt0() { asm volatile("s_waitcnt vmcnt(0)" ::: "memory"); }
__device__ __forceinline__ void vmcnt3() { asm volatile("s_waitcnt vmcnt(3)" ::: "memory"); }
__device__ __forceinline__ void vmcnt4() { asm volatile("s_waitcnt vmcnt(4)" ::: "memory"); }
template<int BN> __device__ __forceinline__ void vmcnt_steady() {
    if constexpr (BN == 256) vmcnt4(); else vmcnt3();
}

// ---------- 8-phase 256-wide mainloop machinery ----------
// Stage one half-tile (NROWS x 64 k-elems, bf16) global -> LDS, with the k-slot
// XOR swizzle applied on the GLOBAL side (global_load_lds dest must be linear).
// LDS layout: row-major [NROWS][64] bf16 (128 B rows); 16B slot s of row r holds
// global k-slot s ^ (r & 7).
template<int NROWS>
__device__ __forceinline__ void stage_half(
    const unsigned short* __restrict__ G, int ld, int grow0, int k0,
    unsigned short* lds, int tid)
{
    const int w = tid >> 6, l = tid & 63;
#pragma unroll
    for (int c = 0; c < NROWS / 64; ++c) {
        const int idx  = (c * 8 + w) * 64 + l;      // 0 .. NROWS*8-1
        const int row  = idx >> 3;                  // local row
        const int slot = (idx & 7) ^ (row & 7);     // pre-swizzled global k-slot
        const unsigned short* ga = G + (size_t)(grow0 + row) * ld + (k0 + slot * 8);
        __builtin_amdgcn_global_load_lds((gptr1)ga, (lptr3)(lds + (c * 8 + w) * 512), 16, 0, 0);
    }
}

// One phase: ds-read frags for (A-half QM, B-half QN) of buffer BUF, issue staging,
// barrier, MFMA cluster under setprio, optional counted vmcnt, barrier.
// Row mapping makes each phase read EXACTLY one A-half and one B-half globally:
//   A row = QM*128 + (w>>2)*64 + mi*16 + lr
//   B row = QN*(BN/2) + (w&3)*(BN/8) + ni*16 + lr
#define PHASE(BUF, QM, QN, STAGES, TAIL)                                              \
  {                                                                                   \
    const unsigned short* Ab = As + (BUF) * (256 * 64);                               \
    const unsigned short* Bb = Bs + (BUF) * (BN * 64);                                \
    bf16x8 af[4][2], bq[NF2][2];                                                      \
    _Pragma("unroll") for (int mi = 0; mi < 4; ++mi)                                  \
      _Pragma("unroll") for (int ks = 0; ks < 2; ++ks) {                              \
        const int row = (QM) * 128 + wrow + mi * 16 + lr;                             \
        af[mi][ks] = *(const bf16x8*)(Ab + row * 64 + (((ks * 4 + kq) ^ (row & 7)) * 8)); \
      }                                                                               \
    _Pragma("unroll") for (int ni = 0; ni < NF2; ++ni)                                \
      _Pragma("unroll") for (int ks = 0; ks < 2; ++ks) {                              \
        const int row = (QN) * (BN / 2) + wcol + ni * 16 + lr;                        \
        bq[ni][ks] = *(const bf16x8*)(Bb + row * 64 + (((ks * 4 + kq) ^ (row & 7)) * 8)); \
      }                                                                               \
    STAGES;                                                                           \
    __builtin_amdgcn_s_barrier();                                                     \
    __builtin_amdgcn_s_setprio(1);                                                    \
    _Pragma("unroll") for (int mi = 0; mi < 4; ++mi)                                  \
      _Pragma("unroll") for (int ni = 0; ni < NF2; ++ni)                              \
        _Pragma("unroll") for (int ks = 0; ks < 2; ++ks)                              \
          acc[(QM) * 4 + mi][(QN) * NF2 + ni] = __builtin_amdgcn_mfma_f32_16x16x32_bf16( \
              af[mi][ks], bq[ni][ks], acc[(QM) * 4 + mi][(QN) * NF2 + ni], 0, 0, 0);  \
    __builtin_amdgcn_s_setprio(0);                                                    \
    TAIL;                                                                             \
    __builtin_amdgcn_s_barrier();                                                     \
  }

// C[rowBase:+256, colBase:+BN] += A[256 x K] * Bt[BN x K]^T, 512 threads / 8 waves.
// Race-free stage ring. Region coverage per iteration I (K-tiles 2I, 2I+1):
//   PH1(reads b0.A0,B0) stage b1.A1 | PH2(b0.A0,B1) stage b1.B1
//   PH3(b0.A1,B0) stage b0'.A0      | PH4(b0.A1,B1) stage b0'.B0 + vmcnt -> b1 ALL ready
//   PH5(b1.A0,B0) stage b0'.A1      | PH6(b1.A0,B1) stage b0'.B1
//   PH7(b1.A1,B0) stage b1'.A0      | PH8(b1.A1,B1) stage b1'.B0 + vmcnt -> b0' ALL ready
// Steady-state invariant entering an iter: b1.{A0,B0} in flight (prev PH7/PH8).
// PROLOGUE must therefore stage buf0 (all 4) AND b1.{A0,B0}  [round-5 NaN bug:
// b1.B0 was missing -> PH5 read uninitialized LDS], then certify buf0 with the
// steady vmcnt (BN=256: 12 issued, vmcnt(4) leaves b1.A0+B0; BN=128: 9, vmcnt(3)).
// Certify checks (BN=256, 2 loads per A-half, 2 per B-half):
//   PH4 tail: outstanding 12 = b1.{A0,B0,A1,B1} + b0'.{A0,B0}; vmcnt(4) -> oldest 8
//             = all of buf1 complete before PH5 reads it.
//   PH8 tail: outstanding 12 = b0'.{A0,B0,A1,B1} + b1'.{A0,B0}; vmcnt(4) -> buf0'.
// (BN=128: B-half is 1 load; 9 outstanding, vmcnt(3) certifies the oldest 6.)
template<int BN>
__device__ __forceinline__ void mainloop8(
    const unsigned short* __restrict__ A, const unsigned short* __restrict__ Bt,
    int lda, int ldb, int rowBase, int colBase, int K,
    unsigned short* As, unsigned short* Bs, f32x4 (&acc)[8][BN / 64])
{
    constexpr int NF2  = BN / 128;      // n-frags per phase (2 or 1)
    constexpr int BNH  = BN / 2;
    constexpr int ABUF = 256 * 64, AH = 128 * 64;
    constexpr int BBUF = BN * 64,  BH = BNH * 64;
    const int tid = threadIdx.x, lane = tid & 63, w = tid >> 6;
    const int wrow = (w >> 2) * 64;
    const int wcol = (w & 3) * (BN / 8);
    const int lr = lane & 15, kq = lane >> 4;
    const int niter = K >> 7;

    // prologue: buf0 all 4 halves + buf1.A0 + buf1.B0; certify buf0
    stage_half<128>(A,  lda, rowBase,       0,  As,        tid);
    stage_half<BNH>(Bt, ldb, colBase,       0,  Bs,        tid);
    stage_half<128>(A,  lda, rowBase + 128, 0,  As + AH,   tid);
    stage_half<BNH>(Bt, ldb, colBase + BNH, 0,  Bs + BH,   tid);
    stage_half<128>(A,  lda, rowBase,       64, As + ABUF, tid);
    stage_half<BNH>(Bt, ldb, colBase,       64, Bs + BBUF, tid);
    vmcnt_steady<BN>();
    __builtin_amdgcn_s_barrier();

    for (int I = 0; I < niter; ++I) {
        const bool nl = (I + 1 < niter);
        const int ke = I << 7;
        PHASE(0, 0, 0, { stage_half<128>(A,  lda, rowBase + 128, ke + 64,  As + ABUF + AH, tid); }, {});
        PHASE(0, 0, 1, { stage_half<BNH>(Bt, ldb, colBase + BNH, ke + 64,  Bs + BBUF + BH, tid); }, {});
        PHASE(0, 1, 0, { if (nl) stage_half<128>(A,  lda, rowBase,       ke + 128, As,      tid); }, {});
        PHASE(0, 1, 1, { if (nl) stage_half<BNH>(Bt, ldb, colBase,       ke + 128, Bs,      tid); },
                       { if (nl) vmcnt_steady<BN>(); else vmcnt0(); });
        PHASE(1, 0, 0, { if (nl) stage_half<128>(A,  lda, rowBase + 128, ke + 128, As + AH, tid); }, {});
        PHASE(1, 0, 1, { if (nl) stage_half<BNH>(Bt, ldb, colBase + BNH, ke + 128, Bs + BH, tid); }, {});
        PHASE(1, 1, 0, { if (nl) stage_half<128>(A,  lda, rowBase,       ke + 192, As + ABUF, tid); }, {});
        PHASE(1, 1, 1, { if (nl) stage_half<BNH>(Bt, ldb, colBase,       ke + 192, Bs + BBUF, tid); },
                       { if (nl) vmcnt_steady<BN>(); });
    }
}

// ---------- prep: normalize text[1] rows -> tn, copy t1 into out, zero L & SS ----------
__global__ __launch_bounds__(256) void prep_tn_k(
    const float* __restrict__ text, unsigned short* __restrict__ tn,
    float* __restrict__ out, float* __restrict__ L, float* __restrict__ SS)
{
    const int m = blockIdx.x;
    const int t = threadIdx.x;  // 256
    const float* t1 = text + (size_t)M_SZ * D_SZ;
    float2 v = ((const float2*)(t1 + (size_t)m * D_SZ))[t];
    float s = v.x * v.x + v.y * v.y;
#pragma unroll
    for (int off = 32; off > 0; off >>= 1) s += __shfl_down(s, off);
    __shared__ float partial[4];
    if ((t & 63) == 0) partial[t >> 6] = s;
    __syncthreads();
    float norm = sqrtf(partial[0] + partial[1] + partial[2] + partial[3]);
    norm = fmaxf(norm, 1e-8f);
    const float inv = 1.f / norm;
    ushort2 pk; pk.x = f2bf(v.x * inv); pk.y = f2bf(v.y * inv);
    ((ushort2*)(tn + (size_t)m * D_SZ))[t] = pk;
#pragma unroll
    for (int b = 0; b < B_SZ; ++b)
        ((float2*)(out + ((size_t)(b * M_SZ + m)) * (2 * D_SZ) + D_SZ))[t] = v;
    if (m < 64) L[m * 256 + t] = 0.f;
    if (m < 128) SS[m * 256 + t] = 0.f;
}

// ---------- prep: transpose W (fp32 [d][e]) -> Wt (bf16 [e][d]) ----------
__global__ __launch_bounds__(256) void prep_w_k(
    const float* __restrict__ W, unsigned short* __restrict__ Wt)
{
    const int dt = blockIdx.x, et = blockIdx.y;
    const int t = threadIdx.x;
    __shared__ unsigned short tile[64][72];
    const int rr = t >> 4;
    const int cc = (t & 15) * 4;
#pragma unroll
    for (int p = 0; p < 4; ++p) {
        const int d = p * 16 + rr;
        const float4 v = *(const float4*)(W + (size_t)(dt * 64 + d) * D_SZ + et * 64 + cc);
        tile[d][cc] = f2bf(v.x); tile[d][cc + 1] = f2bf(v.y);
        tile[d][cc + 2] = f2bf(v.z); tile[d][cc + 3] = f2bf(v.w);
    }
    __syncthreads();
#pragma unroll
    for (int p = 0; p < 4; ++p) {
        const int e = p * 16 + rr;
        ushort4 pk;
        pk.x = tile[cc][e]; pk.y = tile[cc + 1][e]; pk.z = tile[cc + 2][e]; pk.w = tile[cc + 3][e];
        *(ushort4*)(Wt + (size_t)(et * 64 + e) * D_SZ + dt * 64 + cc) = pk;
    }
}

// ---------- features fp32 -> V bf16 [b*n][d] and Vt bf16 [b][d][n] ----------
__global__ __launch_bounds__(256) void convert_feat_k(
    const float* __restrict__ feat, unsigned short* __restrict__ V,
    unsigned short* __restrict__ Vt)
{
    const int nt = blockIdx.x, dt = blockIdx.y, b = blockIdx.z;
    const int t = threadIdx.x;
    __shared__ unsigned short tile[64][72];
    const int rr = t >> 4;
    const int cc = (t & 15) * 4;
#pragma unroll
    for (int p = 0; p < 4; ++p) {
        const int r = p * 16 + rr;
        const size_t grow = (size_t)(b * N_SZ + nt * 64 + r);
        const float4 v = *(const float4*)(feat + grow * D_SZ + dt * 64 + cc);
        ushort4 pk; pk.x = f2bf(v.x); pk.y = f2bf(v.y); pk.z = f2bf(v.z); pk.w = f2bf(v.w);
        *(ushort4*)(V + grow * D_SZ + dt * 64 + cc) = pk;
        tile[r][cc] = pk.x; tile[r][cc + 1] = pk.y; tile[r][cc + 2] = pk.z; tile[r][cc + 3] = pk.w;
    }
    __syncthreads();
#pragma unroll
    for (int p = 0; p < 4; ++p) {
        const int d = p * 16 + rr;
        ushort4 pk;
        pk.x = tile[cc][d]; pk.y = tile[cc + 1][d]; pk.z = tile[cc + 2][d]; pk.w = tile[cc + 3][d];
        *(ushort4*)(Vt + ((size_t)(b * D_SZ + dt * 64 + d)) * N_SZ + nt * 64 + cc) = pk;
    }
}

// ---------- gemm1 (8-phase 256x256): f1b = bf16(V @ Wt^T + bias); SS[row] += sum(f1^2) ----------
__global__ __launch_bounds__(512, 1) void gemm1_k8(
    const unsigned short* __restrict__ V, const unsigned short* __restrict__ Wt,
    const float* __restrict__ bias, unsigned short* __restrict__ f1b,
    float* __restrict__ SS)
{
    __shared__ unsigned short smem[65536];   // 128 KiB staging
    unsigned short* As = smem;
    unsigned short* Bs = smem + 32768;
    f32x4 acc[8][4];
#pragma unroll
    for (int i = 0; i < 8; ++i)
#pragma unroll
        for (int j = 0; j < 4; ++j) acc[i][j] = (f32x4){0.f, 0.f, 0.f, 0.f};

    const int lin = blockIdx.x;              // 256 blocks
    const int rowBase = (lin >> 1) * 256;    // V rows (b*n)
    const int colBase = (lin & 1) * 256;     // e cols

    mainloop8<256>(V, Wt, D_SZ, D_SZ, rowBase, colBase, D_SZ, As, Bs, acc);

    const int tid = threadIdx.x, lane = tid & 63, w = tid >> 6;
    const int wrow = (w >> 2) * 64, wcol = (w & 3) * 32;
    const int lr = lane & 15, kq = lane >> 4;

    // bias per col-frag (invariant over a)
    float bv[4];
    int cs[4];
#pragma unroll
    for (int j = 0; j < 4; ++j) {
        cs[j] = colBase + (j >> 1) * 128 + wcol + (j & 1) * 16 + lr;
        bv[j] = bias[cs[j]];
    }
#pragma unroll
    for (int a = 0; a < 8; ++a) {
        const int r0 = rowBase + (a >> 2) * 128 + wrow + (a & 3) * 16 + kq * 4;
        float s[4] = {0.f, 0.f, 0.f, 0.f};
#pragma unroll
        for (int j = 0; j < 4; ++j) {
#pragma unroll
            for (int r = 0; r < 4; ++r) {
                const float v = acc[a][j][r] + bv[j];
                f1b[(size_t)(r0 + r) * D_SZ + cs[j]] = f2bf(v);
                s[r] += v * v;
            }
        }
#pragma unroll
        for (int off = 1; off <= 8; off <<= 1)
#pragma unroll
            for (int r = 0; r < 4; ++r) s[r] += __shfl_xor(s[r], off);
        if (lr == 0) {
#pragma unroll
            for (int r = 0; r < 4; ++r) atomicAdd(&SS[r0 + r], s[r]);
        }
    }
}

// ---------- gemm2 (8-phase 256x256): sim = (f1b @ tn^T) * invnorm; E = bf16(exp); L += sums ----------
__global__ __launch_bounds__(512, 1) void gemm2_k8(
    const unsigned short* __restrict__ f1b, const unsigned short* __restrict__ tn,
    const float* __restrict__ SS, unsigned short* __restrict__ E,
    float* __restrict__ L)
{
    __shared__ unsigned short smem[65536];   // 128 KiB: staging; reused as swizzled P-tile
    __shared__ float invn[256];              // per-row 1/||f1||
    unsigned short* As = smem;               // [2][256*64]
    unsigned short* Bs = smem + 32768;       // [2][256*64]
    f32x4 acc[8][4];
#pragma unroll
    for (int i = 0; i < 8; ++i)
#pragma unroll
        for (int j = 0; j < 4; ++j) acc[i][j] = (f32x4){0.f, 0.f, 0.f, 0.f};

    const int lin = blockIdx.x;              // 1024 blocks
    const int xcd = lin & 7, slot = lin >> 3;
    const int mt = slot & 7;                 // tn col-tile (inner: tn L2-resident)
    const int rt = (slot >> 3) * 8 + xcd;    // f1 row-tile pinned per XCD
    const int rowBase = rt * 256;            // f1 rows (b*4096 + n)
    const int colBase = mt * 256;            // tn rows (m)

    mainloop8<256>(f1b, tn, D_SZ, D_SZ, rowBase, colBase, D_SZ, As, Bs, acc);

    const int tid = threadIdx.x, lane = tid & 63, w = tid >> 6;
    if (tid < 256) {
        const float ss = SS[rowBase + tid];
        invn[tid] = 1.f / fmaxf(sqrtf(ss), 1e-8f);
    }
    __syncthreads();                         // drains DMA (last iter vmcnt(0)) + publishes invn

    const int wrow = (w >> 2) * 64, wcol = (w & 3) * 32;
    const int lr = lane & 15, kq = lane >> 4;
    const int b = rowBase >> 12;
    const int nb0 = rowBase & 4095;

    // write exp(sim*invnorm) into swizzled P[m 256][n 256] (16B slot s of row m at s^(m&7))
    unsigned short* P = smem;
    float ps[4] = {0.f, 0.f, 0.f, 0.f};
#pragma unroll
    for (int a = 0; a < 8; ++a) {
        const int n0 = (a >> 2) * 128 + wrow + (a & 3) * 16 + kq * 4;   // local n
        const float4 inr = *(const float4*)(invn + n0);
#pragma unroll
        for (int j = 0; j < 4; ++j) {
            const int m = (j >> 1) * 128 + wcol + (j & 1) * 16 + lr;    // local m
            const float e0 = __expf(acc[a][j][0] * inr.x);
            const float e1 = __expf(acc[a][j][1] * inr.y);
            const float e2 = __expf(acc[a][j][2] * inr.z);
            const float e3 = __expf(acc[a][j][3] * inr.w);
            ushort4 pk; pk.x = f2bf(e0); pk.y = f2bf(e1); pk.z = f2bf(e2); pk.w = f2bf(e3);
            *(ushort4*)(P + m * 256 + (((n0 >> 3) ^ (m & 7)) * 8) + (n0 & 7)) = pk;
            ps[j] += (e0 + e1) + (e2 + e3);
        }
    }
#pragma unroll
    for (int j = 0; j < 4; ++j) {
        float p = ps[j];
        p += __shfl_down(p, 16);
        p += __shfl_down(p, 32);
        const int m = (j >> 1) * 128 + wcol + (j & 1) * 16 + lr;
        if (lane < 16) atomicAdd(&L[b * M_SZ + colBase + m], p);
    }
    __syncthreads();

    // coalesced transposed store: 32 lanes cover 512 contiguous bytes along n
    unsigned short* Eb = E + (size_t)b * M_SZ * N_SZ;
#pragma unroll
    for (int c = 0; c < 16; ++c) {
        const int rm = c * 16 + (tid >> 5);
        const int ns = tid & 31;
        bf16x8 v = *(const bf16x8*)(P + rm * 256 + ((ns ^ (rm & 7)) * 8));
        *(bf16x8*)(Eb + (size_t)(colBase + rm) * N_SZ + nb0 + ns * 8) = v;
    }
}

// ---------- gemm3 (8-phase 256x128): fm = (E @ Vt^T) / L -> out left half ----------
// XCD map: b = lin&7 (one batch per XCD -> Vt slice 4 MiB L2-fit; E-tiles
// streamed once, shared by the 4 concurrent dt-blocks of the same (b,mtile)).
__global__ __launch_bounds__(512, 1) void gemm3_k8(
    const unsigned short* __restrict__ E, const unsigned short* __restrict__ Vt,
    const float* __restrict__ L, float* __restrict__ out)
{
    __shared__ unsigned short smem[49152];   // 96 KiB: As 64K + Bs 32K
    unsigned short* As = smem;               // [2][256*64]
    unsigned short* Bs = smem + 32768;       // [2][128*64]
    f32x4 acc[8][2];
#pragma unroll
    for (int i = 0; i < 8; ++i)
#pragma unroll
        for (int j = 0; j < 2; ++j) acc[i][j] = (f32x4){0.f, 0.f, 0.f, 0.f};

    const int lin = blockIdx.x;              // 256 blocks
    const int b = lin & 7;                   // batch pinned per XCD
    const int mtile = (lin >> 3) & 7;        // E m-tile
    const int dt = lin >> 6;                 // Vt d-tile (0..3)
    const int rowBase = mtile * 256;         // m
    const int colBase = dt * 128;            // d

    const unsigned short* Ab = E + (size_t)b * M_SZ * N_SZ;
    const unsigned short* Bb = Vt + (size_t)b * D_SZ * N_SZ;
    mainloop8<128>(Ab, Bb, N_SZ, N_SZ, rowBase, colBase, N_SZ, As, Bs, acc);

    const int tid = threadIdx.x, lane = tid & 63, w = tid >> 6;
    const int wrow = (w >> 2) * 64, wcol = (w & 3) * 16;
    const int lr = lane & 15, kq = lane >> 4;

#pragma unroll
    for (int a = 0; a < 8; ++a) {
        const int r0 = rowBase + (a >> 2) * 128 + wrow + (a & 3) * 16 + kq * 4;
        float invl[4];
#pragma unroll
        for (int r = 0; r < 4; ++r) invl[r] = 1.f / L[b * M_SZ + r0 + r];
#pragma unroll
        for (int j = 0; j < 2; ++j) {
            const int d = colBase + j * 64 + wcol + lr;
#pragma unroll
            for (int r = 0; r < 4; ++r)
                out[((size_t)(b * M_SZ + r0 + r)) * (2 * D_SZ) + d] = acc[a][j][r] * invl[r];
        }
    }
}

extern "C" void kernel_launch(void* const* d_in, const int* in_sizes, int n_in,
                              void* d_out, int out_size, void* d_ws, size_t ws_size,
                              hipStream_t stream) {
    const float* features = (const float*)d_in[0];   // [8, 4096, 512]
    const float* text     = (const float*)d_in[1];   // [2, 2048, 512]
    const float* W        = (const float*)d_in[2];   // [512, 512]
    const float* bias     = (const float*)d_in[3];   // [512]
    float* out = (float*)d_out;                      // [8, 2048, 1024]
    char* ws = (char*)d_ws;

    // workspace layout (bytes)
    unsigned short* f1b = (unsigned short*)(ws + 0);            // 32 MiB (lives through gemm2)
    unsigned short* tn  = (unsigned short*)(ws + 33554432);     //  2 MiB
    unsigned short* Wt  = (unsigned short*)(ws + 35651584);     // .5 MiB
    unsigned short* V   = (unsigned short*)(ws + 36175872);     // 32 MiB
    unsigned short* Vt  = (unsigned short*)(ws + 69730304);     // 32 MiB
    float*          L   = (float*)(ws + 103284736);             // 64 KiB
    float*          SS  = (float*)(ws + 103350272);             // 128 KiB
    unsigned short* E   = (unsigned short*)(ws + 103481344);    // 128 MiB

    hipLaunchKernelGGL(prep_tn_k, dim3(M_SZ), dim3(256), 0, stream, text, tn, out, L, SS);
    hipLaunchKernelGGL(prep_w_k, dim3(8, 8), dim3(256), 0, stream, W, Wt);
    hipLaunchKernelGGL(convert_feat_k, dim3(64, 8, 8), dim3(256), 0, stream, features, V, Vt);
    hipLaunchKernelGGL(gemm1_k8, dim3(256), dim3(512), 0, stream, V, Wt, bias, f1b, SS);
    hipLaunchKernelGGL(gemm2_k8, dim3(1024), dim3(512), 0, stream, f1b, tn, SS, E, L);
    hipLaunchKernelGGL(gemm3_k8, dim3(256), dim3(512), 0, stream, E, Vt, L, out);
}

// Round 7
// 354.053 us; speedup vs baseline: 1.0627x; 1.0131x over previous
//
#include <hip/hip_runtime.h>

#define B_SZ 8
#define N_SZ 4096
#define M_SZ 2048
#define D_SZ 512

typedef __attribute__((ext_vector_type(8))) short bf16x8;
typedef __attribute__((ext_vector_type(4))) float f32x4;
typedef __attribute__((address_space(1))) const void* gptr1;
typedef __attribute__((address_space(3))) void* lptr3;

__device__ __forceinline__ unsigned short f2bf(float x) {
    unsigned int u = __builtin_bit_cast(unsigned int, x);
    u += 0x7fffu + ((u >> 16) & 1u);
    return (unsigned short)(u >> 16);
}
__device__ __forceinline__ float bf2f(unsigned short u) {
    unsigned int x = ((unsigned int)u) << 16;
    return __builtin_bit_cast(float, x);
}

__device__ __forceinline__ void vmcnt0() { asm volatile("s_waitcnt vmcnt(0)" ::: "memory"); }
__device__ __forceinline__ void vmcnt3() { asm volatile("s_waitcnt vmcnt(3)" ::: "memory"); }
__device__ __forceinline__ void vmcnt4() { asm volatile("s_waitcnt vmcnt(4)" ::: "memory"); }
template<int BN> __device__ __forceinline__ void vmcnt_steady() {
    if constexpr (BN == 256) vmcnt4(); else vmcnt3();
}

// ---------- 8-phase 256-wide mainloop, register-cached operand frags ----------
// Stage one half-tile (NROWS x 64 k-elems, bf16) global -> LDS, with the k-slot
// XOR swizzle applied on the GLOBAL side (global_load_lds dest must be linear).
// LDS layout: row-major [NROWS][64] bf16 (128 B rows); 16B slot s of row r holds
// global k-slot s ^ (r & 7).
template<int NROWS>
__device__ __forceinline__ void stage_half(
    const unsigned short* __restrict__ G, int ld, int grow0, int k0,
    unsigned short* lds, int tid)
{
    const int w = tid >> 6, l = tid & 63;
#pragma unroll
    for (int c = 0; c < NROWS / 64; ++c) {
        const int idx  = (c * 8 + w) * 64 + l;      // 0 .. NROWS*8-1
        const int row  = idx >> 3;                  // local row
        const int slot = (idx & 7) ^ (row & 7);     // pre-swizzled global k-slot
        const unsigned short* ga = G + (size_t)(grow0 + row) * ld + (k0 + slot * 8);
        __builtin_amdgcn_global_load_lds((gptr1)ga, (lptr3)(lds + (c * 8 + w) * 512), 16, 0, 0);
    }
}

// Fragment reads (register-cached across phases — LDS traffic halved vs naive):
// per K-tile window: ph_a reads af(QM0)+bq0, ph_b reads bq1 only, ph_c reads
// af(QM1) only, ph_d reads NOTHING (af+bq0 still live in registers).
#define PH_RA(BUF, QM)                                                                \
    _Pragma("unroll") for (int mi = 0; mi < 4; ++mi)                                  \
      _Pragma("unroll") for (int ks = 0; ks < 2; ++ks) {                              \
        const int row = (QM) * 128 + wrow + mi * 16 + lr;                             \
        af[mi][ks] = *(const bf16x8*)(As + (BUF) * ABUF + row * 64 + (((ks * 4 + kq) ^ (row & 7)) * 8)); \
      }

#define PH_RB(BUF, QN, DST)                                                           \
    _Pragma("unroll") for (int ni = 0; ni < NF2; ++ni)                                \
      _Pragma("unroll") for (int ks = 0; ks < 2; ++ks) {                              \
        const int row = (QN) * (BN / 2) + wcol + ni * 16 + lr;                        \
        DST[ni][ks] = *(const bf16x8*)(Bs + (BUF) * BBUF + row * 64 + (((ks * 4 + kq) ^ (row & 7)) * 8)); \
      }

// MFMA cluster for quadrant (QM,QN) using B-frags BQ; stage issue before the
// barrier, counted-vmcnt tail after the MFMAs.
#define PH_MMA(QM, QN, BQ, STAGES, TAIL)                                              \
  {                                                                                   \
    STAGES;                                                                           \
    __builtin_amdgcn_s_barrier();                                                     \
    __builtin_amdgcn_s_setprio(1);                                                    \
    _Pragma("unroll") for (int mi = 0; mi < 4; ++mi)                                  \
      _Pragma("unroll") for (int ni = 0; ni < NF2; ++ni)                              \
        _Pragma("unroll") for (int ks = 0; ks < 2; ++ks)                              \
          acc[(QM) * 4 + mi][(QN) * NF2 + ni] = __builtin_amdgcn_mfma_f32_16x16x32_bf16( \
              af[mi][ks], BQ[ni][ks], acc[(QM) * 4 + mi][(QN) * NF2 + ni], 0, 0, 0);  \
    __builtin_amdgcn_s_setprio(0);                                                    \
    TAIL;                                                                             \
    __builtin_amdgcn_s_barrier();                                                     \
  }

// C[rowBase:+256, colBase:+BN] += A[256 x K] * Bt[BN x K]^T, 512 threads / 8 waves.
// Phase order per window: (QM0,QN0) -> (QM0,QN1) -> (QM1,QN1) -> (QM1,QN0).
// Stage ring (unchanged slots; every region's last LDS-reader is now EARLIER
// thanks to reg-caching, so all placements have extra slack):
//   ph1 stage b1.A1  | ph2 stage b1.B1 | ph3 stage b0'.A0 | ph4 stage b0'.B0 +vmcnt->b1 ready
//   ph5 stage b0'.A1 | ph6 stage b0'.B1| ph7 stage b1'.A0 | ph8 stage b1'.B0 +vmcnt->b0' ready
// Last LDS-reads: b.A0@ph1/5, b.B0@ph1/5 (reg-cached to ph4/8), b.B1@ph2/6, b.A1@ph3/7.
// Certify (BN=256, 2 loads per half [B-half 1 load at BN=128]):
//   ph4 tail: outstanding 12 = b1.{A0,B0}(prev/prologue)+b1.{A1,B1}+b0'.{A0,B0};
//             vmcnt(4) completes oldest 8 = ALL of b1 before ph5.  [BN=128: 9, vmcnt(3)]
//   ph8 tail: symmetric for b0'.
// Prologue: buf0 all 4 halves + b1.{A0,B0}; vmcnt_steady certifies buf0.
template<int BN>
__device__ __forceinline__ void mainloop8(
    const unsigned short* __restrict__ A, const unsigned short* __restrict__ Bt,
    int lda, int ldb, int rowBase, int colBase, int K,
    unsigned short* As, unsigned short* Bs, f32x4 (&acc)[8][BN / 64])
{
    constexpr int NF2  = BN / 128;      // n-frags per phase (2 or 1)
    constexpr int BNH  = BN / 2;
    constexpr int ABUF = 256 * 64, AH = 128 * 64;
    constexpr int BBUF = BN * 64,  BH = BNH * 64;
    const int tid = threadIdx.x, lane = tid & 63, w = tid >> 6;
    const int wrow = (w >> 2) * 64;
    const int wcol = (w & 3) * (BN / 8);
    const int lr = lane & 15, kq = lane >> 4;
    const int niter = K >> 7;

    bf16x8 af[4][2], bq0[NF2][2], bq1[NF2][2];   // all indices compile-time (no scratch)

    // prologue: buf0 all 4 halves + b1.A0 + b1.B0; certify buf0
    stage_half<128>(A,  lda, rowBase,       0,  As,        tid);
    stage_half<BNH>(Bt, ldb, colBase,       0,  Bs,        tid);
    stage_half<128>(A,  lda, rowBase + 128, 0,  As + AH,   tid);
    stage_half<BNH>(Bt, ldb, colBase + BNH, 0,  Bs + BH,   tid);
    stage_half<128>(A,  lda, rowBase,       64, As + ABUF, tid);
    stage_half<BNH>(Bt, ldb, colBase,       64, Bs + BBUF, tid);
    vmcnt_steady<BN>();
    __builtin_amdgcn_s_barrier();

    for (int I = 0; I < niter; ++I) {
        const bool nl = (I + 1 < niter);
        const int ke = I << 7;
        // ---- buf0 window (K-tile 2I) ----
        PH_RA(0, 0) PH_RB(0, 0, bq0)
        PH_MMA(0, 0, bq0, { stage_half<128>(A,  lda, rowBase + 128, ke + 64,  As + ABUF + AH, tid); }, {})
        PH_RB(0, 1, bq1)
        PH_MMA(0, 1, bq1, { stage_half<BNH>(Bt, ldb, colBase + BNH, ke + 64,  Bs + BBUF + BH, tid); }, {})
        PH_RA(0, 1)
        PH_MMA(1, 1, bq1, { if (nl) stage_half<128>(A,  lda, rowBase,       ke + 128, As,      tid); }, {})
        PH_MMA(1, 0, bq0, { if (nl) stage_half<BNH>(Bt, ldb, colBase,       ke + 128, Bs,      tid); },
                          { if (nl) vmcnt_steady<BN>(); else vmcnt0(); })
        // ---- buf1 window (K-tile 2I+1) ----
        PH_RA(1, 0) PH_RB(1, 0, bq0)
        PH_MMA(0, 0, bq0, { if (nl) stage_half<128>(A,  lda, rowBase + 128, ke + 128, As + AH, tid); }, {})
        PH_RB(1, 1, bq1)
        PH_MMA(0, 1, bq1, { if (nl) stage_half<BNH>(Bt, ldb, colBase + BNH, ke + 128, Bs + BH, tid); }, {})
        PH_RA(1, 1)
        PH_MMA(1, 1, bq1, { if (nl) stage_half<128>(A,  lda, rowBase,       ke + 192, As + ABUF, tid); }, {})
        PH_MMA(1, 0, bq0, { if (nl) stage_half<BNH>(Bt, ldb, colBase,       ke + 192, Bs + BBUF, tid); },
                          { if (nl) vmcnt_steady<BN>(); })
    }
}

// ---------- prep: normalize text[1] rows -> tn, copy t1 into out, zero L & SS ----------
__global__ __launch_bounds__(256) void prep_tn_k(
    const float* __restrict__ text, unsigned short* __restrict__ tn,
    float* __restrict__ out, float* __restrict__ L, float* __restrict__ SS)
{
    const int m = blockIdx.x;
    const int t = threadIdx.x;  // 256
    const float* t1 = text + (size_t)M_SZ * D_SZ;
    float2 v = ((const float2*)(t1 + (size_t)m * D_SZ))[t];
    float s = v.x * v.x + v.y * v.y;
#pragma unroll
    for (int off = 32; off > 0; off >>= 1) s += __shfl_down(s, off);
    __shared__ float partial[4];
    if ((t & 63) == 0) partial[t >> 6] = s;
    __syncthreads();
    float norm = sqrtf(partial[0] + partial[1] + partial[2] + partial[3]);
    norm = fmaxf(norm, 1e-8f);
    const float inv = 1.f / norm;
    ushort2 pk; pk.x = f2bf(v.x * inv); pk.y = f2bf(v.y * inv);
    ((ushort2*)(tn + (size_t)m * D_SZ))[t] = pk;
#pragma unroll
    for (int b = 0; b < B_SZ; ++b)
        ((float2*)(out + ((size_t)(b * M_SZ + m)) * (2 * D_SZ) + D_SZ))[t] = v;
    if (m < 64) L[m * 256 + t] = 0.f;
    if (m < 128) SS[m * 256 + t] = 0.f;
}

// ---------- prep: transpose W (fp32 [d][e]) -> Wt (bf16 [e][d]) ----------
__global__ __launch_bounds__(256) void prep_w_k(
    const float* __restrict__ W, unsigned short* __restrict__ Wt)
{
    const int dt = blockIdx.x, et = blockIdx.y;
    const int t = threadIdx.x;
    __shared__ unsigned short tile[64][72];
    const int rr = t >> 4;
    const int cc = (t & 15) * 4;
#pragma unroll
    for (int p = 0; p < 4; ++p) {
        const int d = p * 16 + rr;
        const float4 v = *(const float4*)(W + (size_t)(dt * 64 + d) * D_SZ + et * 64 + cc);
        tile[d][cc] = f2bf(v.x); tile[d][cc + 1] = f2bf(v.y);
        tile[d][cc + 2] = f2bf(v.z); tile[d][cc + 3] = f2bf(v.w);
    }
    __syncthreads();
#pragma unroll
    for (int p = 0; p < 4; ++p) {
        const int e = p * 16 + rr;
        ushort4 pk;
        pk.x = tile[cc][e]; pk.y = tile[cc + 1][e]; pk.z = tile[cc + 2][e]; pk.w = tile[cc + 3][e];
        *(ushort4*)(Wt + (size_t)(et * 64 + e) * D_SZ + dt * 64 + cc) = pk;
    }
}

// ---------- features fp32 -> V bf16 [b*n][d] and Vt bf16 [b][d][n] ----------
__global__ __launch_bounds__(256) void convert_feat_k(
    const float* __restrict__ feat, unsigned short* __restrict__ V,
    unsigned short* __restrict__ Vt)
{
    const int nt = blockIdx.x, dt = blockIdx.y, b = blockIdx.z;
    const int t = threadIdx.x;
    __shared__ unsigned short tile[64][72];
    const int rr = t >> 4;
    const int cc = (t & 15) * 4;
#pragma unroll
    for (int p = 0; p < 4; ++p) {
        const int r = p * 16 + rr;
        const size_t grow = (size_t)(b * N_SZ + nt * 64 + r);
        const float4 v = *(const float4*)(feat + grow * D_SZ + dt * 64 + cc);
        ushort4 pk; pk.x = f2bf(v.x); pk.y = f2bf(v.y); pk.z = f2bf(v.z); pk.w = f2bf(v.w);
        *(ushort4*)(V + grow * D_SZ + dt * 64 + cc) = pk;
        tile[r][cc] = pk.x; tile[r][cc + 1] = pk.y; tile[r][cc + 2] = pk.z; tile[r][cc + 3] = pk.w;
    }
    __syncthreads();
#pragma unroll
    for (int p = 0; p < 4; ++p) {
        const int d = p * 16 + rr;
        ushort4 pk;
        pk.x = tile[cc][d]; pk.y = tile[cc + 1][d]; pk.z = tile[cc + 2][d]; pk.w = tile[cc + 3][d];
        *(ushort4*)(Vt + ((size_t)(b * D_SZ + dt * 64 + d)) * N_SZ + nt * 64 + cc) = pk;
    }
}

// ---------- gemm1 (8-phase 256x256): f1b = bf16(V @ Wt^T + bias); SS[row] += sum(f1^2) ----------
__global__ __launch_bounds__(512, 1) void gemm1_k8(
    const unsigned short* __restrict__ V, const unsigned short* __restrict__ Wt,
    const float* __restrict__ bias, unsigned short* __restrict__ f1b,
    float* __restrict__ SS)
{
    __shared__ unsigned short smem[65536];   // 128 KiB staging
    unsigned short* As = smem;
    unsigned short* Bs = smem + 32768;
    f32x4 acc[8][4];
#pragma unroll
    for (int i = 0; i < 8; ++i)
#pragma unroll
        for (int j = 0; j < 4; ++j) acc[i][j] = (f32x4){0.f, 0.f, 0.f, 0.f};

    const int lin = blockIdx.x;              // 256 blocks
    const int rowBase = (lin >> 1) * 256;    // V rows (b*n)
    const int colBase = (lin & 1) * 256;     // e cols

    mainloop8<256>(V, Wt, D_SZ, D_SZ, rowBase, colBase, D_SZ, As, Bs, acc);

    const int tid = threadIdx.x, lane = tid & 63, w = tid >> 6;
    const int wrow = (w >> 2) * 64, wcol = (w & 3) * 32;
    const int lr = lane & 15, kq = lane >> 4;

    // bias per col-frag (invariant over a)
    float bv[4];
    int cs[4];
#pragma unroll
    for (int j = 0; j < 4; ++j) {
        cs[j] = colBase + (j >> 1) * 128 + wcol + (j & 1) * 16 + lr;
        bv[j] = bias[cs[j]];
    }
#pragma unroll
    for (int a = 0; a < 8; ++a) {
        const int r0 = rowBase + (a >> 2) * 128 + wrow + (a & 3) * 16 + kq * 4;
        float s[4] = {0.f, 0.f, 0.f, 0.f};
#pragma unroll
        for (int j = 0; j < 4; ++j) {
#pragma unroll
            for (int r = 0; r < 4; ++r) {
                const float v = acc[a][j][r] + bv[j];
                f1b[(size_t)(r0 + r) * D_SZ + cs[j]] = f2bf(v);
                s[r] += v * v;
            }
        }
#pragma unroll
        for (int off = 1; off <= 8; off <<= 1)
#pragma unroll
            for (int r = 0; r < 4; ++r) s[r] += __shfl_xor(s[r], off);
        if (lr == 0) {
#pragma unroll
            for (int r = 0; r < 4; ++r) atomicAdd(&SS[r0 + r], s[r]);
        }
    }
}

// ---------- gemm2 (8-phase 256x256): sim = (f1b @ tn^T) * invnorm; E = bf16(exp); L += sums ----------
__global__ __launch_bounds__(512, 1) void gemm2_k8(
    const unsigned short* __restrict__ f1b, const unsigned short* __restrict__ tn,
    const float* __restrict__ SS, unsigned short* __restrict__ E,
    float* __restrict__ L)
{
    __shared__ unsigned short smem[65536];   // 128 KiB: staging; reused as swizzled P-tile
    __shared__ float invn[256];              // per-row 1/||f1||
    unsigned short* As = smem;               // [2][256*64]
    unsigned short* Bs = smem + 32768;       // [2][256*64]
    f32x4 acc[8][4];
#pragma unroll
    for (int i = 0; i < 8; ++i)
#pragma unroll
        for (int j = 0; j < 4; ++j) acc[i][j] = (f32x4){0.f, 0.f, 0.f, 0.f};

    const int lin = blockIdx.x;              // 1024 blocks
    const int xcd = lin & 7, slot = lin >> 3;
    const int mt = slot & 7;                 // tn col-tile (inner: tn L2-resident)
    const int rt = (slot >> 3) * 8 + xcd;    // f1 row-tile pinned per XCD
    const int rowBase = rt * 256;            // f1 rows (b*4096 + n)
    const int colBase = mt * 256;            // tn rows (m)

    mainloop8<256>(f1b, tn, D_SZ, D_SZ, rowBase, colBase, D_SZ, As, Bs, acc);

    const int tid = threadIdx.x, lane = tid & 63, w = tid >> 6;
    if (tid < 256) {
        const float ss = SS[rowBase + tid];
        invn[tid] = 1.f / fmaxf(sqrtf(ss), 1e-8f);
    }
    __syncthreads();                         // drains DMA (last iter vmcnt(0)) + publishes invn

    const int wrow = (w >> 2) * 64, wcol = (w & 3) * 32;
    const int lr = lane & 15, kq = lane >> 4;
    const int b = rowBase >> 12;
    const int nb0 = rowBase & 4095;

    // write exp(sim*invnorm) into swizzled P[m 256][n 256] (16B slot s of row m at s^(m&7))
    unsigned short* P = smem;
    float ps[4] = {0.f, 0.f, 0.f, 0.f};
#pragma unroll
    for (int a = 0; a < 8; ++a) {
        const int n0 = (a >> 2) * 128 + wrow + (a & 3) * 16 + kq * 4;   // local n
        const float4 inr = *(const float4*)(invn + n0);
#pragma unroll
        for (int j = 0; j < 4; ++j) {
            const int m = (j >> 1) * 128 + wcol + (j & 1) * 16 + lr;    // local m
            const float e0 = __expf(acc[a][j][0] * inr.x);
            const float e1 = __expf(acc[a][j][1] * inr.y);
            const float e2 = __expf(acc[a][j][2] * inr.z);
            const float e3 = __expf(acc[a][j][3] * inr.w);
            ushort4 pk; pk.x = f2bf(e0); pk.y = f2bf(e1); pk.z = f2bf(e2); pk.w = f2bf(e3);
            *(ushort4*)(P + m * 256 + (((n0 >> 3) ^ (m & 7)) * 8) + (n0 & 7)) = pk;
            ps[j] += (e0 + e1) + (e2 + e3);
        }
    }
#pragma unroll
    for (int j = 0; j < 4; ++j) {
        float p = ps[j];
        p += __shfl_down(p, 16);
        p += __shfl_down(p, 32);
        const int m = (j >> 1) * 128 + wcol + (j & 1) * 16 + lr;
        if (lane < 16) atomicAdd(&L[b * M_SZ + colBase + m], p);
    }
    __syncthreads();

    // coalesced transposed store: 32 lanes cover 512 contiguous bytes along n
    unsigned short* Eb = E + (size_t)b * M_SZ * N_SZ;
#pragma unroll
    for (int c = 0; c < 16; ++c) {
        const int rm = c * 16 + (tid >> 5);
        const int ns = tid & 31;
        bf16x8 v = *(const bf16x8*)(P + rm * 256 + ((ns ^ (rm & 7)) * 8));
        *(bf16x8*)(Eb + (size_t)(colBase + rm) * N_SZ + nb0 + ns * 8) = v;
    }
}

// ---------- gemm3 (8-phase 256x128): fm = (E @ Vt^T) / L -> out left half ----------
// XCD map: b = lin&7 (one batch per XCD -> Vt slice 4 MiB L2-fit; E-tiles
// streamed once, shared by the 4 concurrent dt-blocks of the same (b,mtile)).
__global__ __launch_bounds__(512, 1) void gemm3_k8(
    const unsigned short* __restrict__ E, const unsigned short* __restrict__ Vt,
    const float* __restrict__ L, float* __restrict__ out)
{
    __shared__ unsigned short smem[49152];   // 96 KiB: As 64K + Bs 32K
    unsigned short* As = smem;               // [2][256*64]
    unsigned short* Bs = smem + 32768;       // [2][128*64]
    f32x4 acc[8][2];
#pragma unroll
    for (int i = 0; i < 8; ++i)
#pragma unroll
        for (int j = 0; j < 2; ++j) acc[i][j] = (f32x4){0.f, 0.f, 0.f, 0.f};

    const int lin = blockIdx.x;              // 256 blocks
    const int b = lin & 7;                   // batch pinned per XCD
    const int mtile = (lin >> 3) & 7;        // E m-tile
    const int dt = lin >> 6;                 // Vt d-tile (0..3)
    const int rowBase = mtile * 256;         // m
    const int colBase = dt * 128;            // d

    const unsigned short* Ab = E + (size_t)b * M_SZ * N_SZ;
    const unsigned short* Bb = Vt + (size_t)b * D_SZ * N_SZ;
    mainloop8<128>(Ab, Bb, N_SZ, N_SZ, rowBase, colBase, N_SZ, As, Bs, acc);

    const int tid = threadIdx.x, lane = tid & 63, w = tid >> 6;
    const int wrow = (w >> 2) * 64, wcol = (w & 3) * 16;
    const int lr = lane & 15, kq = lane >> 4;

#pragma unroll
    for (int a = 0; a < 8; ++a) {
        const int r0 = rowBase + (a >> 2) * 128 + wrow + (a & 3) * 16 + kq * 4;
        float invl[4];
#pragma unroll
        for (int r = 0; r < 4; ++r) invl[r] = 1.f / L[b * M_SZ + r0 + r];
#pragma unroll
        for (int j = 0; j < 2; ++j) {
            const int d = colBase + j * 64 + wcol + lr;
#pragma unroll
            for (int r = 0; r < 4; ++r)
                out[((size_t)(b * M_SZ + r0 + r)) * (2 * D_SZ) + d] = acc[a][j][r] * invl[r];
        }
    }
}

extern "C" void kernel_launch(void* const* d_in, const int* in_sizes, int n_in,
                              void* d_out, int out_size, void* d_ws, size_t ws_size,
                              hipStream_t stream) {
    const float* features = (const float*)d_in[0];   // [8, 4096, 512]
    const float* text     = (const float*)d_in[1];   // [2, 2048, 512]
    const float* W        = (const float*)d_in[2];   // [512, 512]
    const float* bias     = (const float*)d_in[3];   // [512]
    float* out = (float*)d_out;                      // [8, 2048, 1024]
    char* ws = (char*)d_ws;

    // workspace layout (bytes)
    unsigned short* f1b = (unsigned short*)(ws + 0);            // 32 MiB (lives through gemm2)
    unsigned short* tn  = (unsigned short*)(ws + 33554432);     //  2 MiB
    unsigned short* Wt  = (unsigned short*)(ws + 35651584);     // .5 MiB
    unsigned short* V   = (unsigned short*)(ws + 36175872);     // 32 MiB
    unsigned short* Vt  = (unsigned short*)(ws + 69730304);     // 32 MiB
    float*          L   = (float*)(ws + 103284736);             // 64 KiB
    float*          SS  = (float*)(ws + 103350272);             // 128 KiB
    unsigned short* E   = (unsigned short*)(ws + 103481344);    // 128 MiB

    hipLaunchKernelGGL(prep_tn_k, dim3(M_SZ), dim3(256), 0, stream, text, tn, out, L, SS);
    hipLaunchKernelGGL(prep_w_k, dim3(8, 8), dim3(256), 0, stream, W, Wt);
    hipLaunchKernelGGL(convert_feat_k, dim3(64, 8, 8), dim3(256), 0, stream, features, V, Vt);
    hipLaunchKernelGGL(gemm1_k8, dim3(256), dim3(512), 0, stream, V, Wt, bias, f1b, SS);
    hipLaunchKernelGGL(gemm2_k8, dim3(1024), dim3(512), 0, stream, f1b, tn, SS, E, L);
    hipLaunchKernelGGL(gemm3_k8, dim3(256), dim3(512), 0, stream, E, Vt, L, out);
}

// Round 8
// 351.077 us; speedup vs baseline: 1.0717x; 1.0085x over previous
//
#include <hip/hip_runtime.h>

#define B_SZ 8
#define N_SZ 4096
#define M_SZ 2048
#define D_SZ 512

typedef __attribute__((ext_vector_type(8))) short bf16x8;
typedef __attribute__((ext_vector_type(4))) float f32x4;
typedef __attribute__((address_space(1))) const void* gptr1;
typedef __attribute__((address_space(3))) void* lptr3;

__device__ __forceinline__ unsigned short f2bf(float x) {
    unsigned int u = __builtin_bit_cast(unsigned int, x);
    u += 0x7fffu + ((u >> 16) & 1u);
    return (unsigned short)(u >> 16);
}
__device__ __forceinline__ float bf2f(unsigned short u) {
    unsigned int x = ((unsigned int)u) << 16;
    return __builtin_bit_cast(float, x);
}

__device__ __forceinline__ void vmcnt0() { asm volatile("s_waitcnt vmcnt(0)" ::: "memory"); }
__device__ __forceinline__ void vmcnt4() { asm volatile("s_waitcnt vmcnt(4)" ::: "memory"); }
__device__ __forceinline__ void vmcnt6() { asm volatile("s_waitcnt vmcnt(6)" ::: "memory"); }
template<int BN> __device__ __forceinline__ void vmcnt_steady() {
    if constexpr (BN == 256) vmcnt6(); else vmcnt4();
}

// ---------- 8-phase 256-wide mainloop, register-cached frags, 3-half-deep ring ----------
// Stage one half-tile (NROWS x 64 k-elems, bf16) global -> LDS, with the k-slot
// XOR swizzle applied on the GLOBAL side (global_load_lds dest must be linear).
// LDS layout: row-major [NROWS][64] bf16 (128 B rows); 16B slot s of row r holds
// global k-slot s ^ (r & 7).
template<int NROWS>
__device__ __forceinline__ void stage_half(
    const unsigned short* __restrict__ G, int ld, int grow0, int k0,
    unsigned short* lds, int tid)
{
    const int w = tid >> 6, l = tid & 63;
#pragma unroll
    for (int c = 0; c < NROWS / 64; ++c) {
        const int idx  = (c * 8 + w) * 64 + l;      // 0 .. NROWS*8-1
        const int row  = idx >> 3;                  // local row
        const int slot = (idx & 7) ^ (row & 7);     // pre-swizzled global k-slot
        const unsigned short* ga = G + (size_t)(grow0 + row) * ld + (k0 + slot * 8);
        __builtin_amdgcn_global_load_lds((gptr1)ga, (lptr3)(lds + (c * 8 + w) * 512), 16, 0, 0);
    }
}

// Fragment reads (register-cached across phases): per K-tile window: ph_a reads
// af(QM0)+bq0, ph_b reads bq1 only, ph_c reads af(QM1) only, ph_d reads nothing.
#define PH_RA(BUF, QM)                                                                \
    _Pragma("unroll") for (int mi = 0; mi < 4; ++mi)                                  \
      _Pragma("unroll") for (int ks = 0; ks < 2; ++ks) {                              \
        const int row = (QM) * 128 + wrow + mi * 16 + lr;                             \
        af[mi][ks] = *(const bf16x8*)(As + (BUF) * ABUF + row * 64 + (((ks * 4 + kq) ^ (row & 7)) * 8)); \
      }

#define PH_RB(BUF, QN, DST)                                                           \
    _Pragma("unroll") for (int ni = 0; ni < NF2; ++ni)                                \
      _Pragma("unroll") for (int ks = 0; ks < 2; ++ks) {                              \
        const int row = (QN) * (BN / 2) + wcol + ni * 16 + lr;                        \
        DST[ni][ks] = *(const bf16x8*)(Bs + (BUF) * BBUF + row * 64 + (((ks * 4 + kq) ^ (row & 7)) * 8)); \
      }

// MFMA cluster for quadrant (QM,QN) using B-frags BQ; stage issue before the
// barrier, counted-vmcnt tail after the MFMAs.
#define PH_MMA(QM, QN, BQ, STAGES, TAIL)                                              \
  {                                                                                   \
    STAGES;                                                                           \
    __builtin_amdgcn_s_barrier();                                                     \
    __builtin_amdgcn_s_setprio(1);                                                    \
    _Pragma("unroll") for (int mi = 0; mi < 4; ++mi)                                  \
      _Pragma("unroll") for (int ni = 0; ni < NF2; ++ni)                              \
        _Pragma("unroll") for (int ks = 0; ks < 2; ++ks)                              \
          acc[(QM) * 4 + mi][(QN) * NF2 + ni] = __builtin_amdgcn_mfma_f32_16x16x32_bf16( \
              af[mi][ks], BQ[ni][ks], acc[(QM) * 4 + mi][(QN) * NF2 + ni], 0, 0, 0);  \
    __builtin_amdgcn_s_setprio(0);                                                    \
    TAIL;                                                                             \
    __builtin_amdgcn_s_barrier();                                                     \
  }

// C[rowBase:+256, colBase:+BN] += A[256 x K] * Bt[BN x K]^T, 512 threads / 8 waves.
// Phase order per window: (QM0,QN0) -> (QM0,QN1) -> (QM1,QN1) -> (QM1,QN0).
// DEEP stage ring (3 half-tiles in flight at every certify; lead 3-6 phases):
//   ph1 stage b1.A1 (UNCOND: this iter's buf1.A1) | ph2 stage b0'.A0
//   ph3 stage b0'.B0 | ph4 stage b0'.B1 + vmcnt_steady -> buf1 ALL certified
//   ph5 stage b0'.A1 | ph6 stage b1'.A0 | ph7 stage b1'.B0
//   ph8 stage b1'.B1 + vmcnt_steady -> buf0' ALL certified
// Region safety (stage >= 1 barrier after region's last ds_read):
//   b1.A1@ph1 (region read prev ph7) | b0'.A0@ph2 (read ph1) | b0'.B0@ph3 (ph1)
//   b0'.B1@ph4 (ph2) | b0'.A1@ph5 (ph3) | b1'.A0@ph6 (ph5) | b1'.B0@ph7 (ph5)
//   b1'.B1@ph8 (ph6). First reads: buf0' @ next ph1 (after ph8 certify ✓),
//   buf1 @ ph5 (after ph4 certify ✓; b1.A1 staged ph1, lead 3).
// Certify math (BN=256, 2 loads/half; BN=128: A-half 2, B-half 1):
//   ph4 tail: outstanding b1.{A0,B0,B1}(prev/prologue)+b1.A1+b0'.{A0,B0,B1} = 14;
//     vmcnt(6) keeps newest 3 halves -> b1 complete.      [BN=128: 10, vmcnt(4)]
//   ph8 tail: b0'.{A0,B0,B1,A1}+b1'.{A0,B0,B1} = 14; vmcnt(6) -> b0' complete.
// Prologue: buf0 all 4 + b1.{A0,B0,B1} (7 halves); vmcnt_steady certifies buf0.
// Last iter: ph2-8 stages skipped; ph4 tail vmcnt(0) drains buf1; ph8 no-op.
template<int BN>
__device__ __forceinline__ void mainloop8(
    const unsigned short* __restrict__ A, const unsigned short* __restrict__ Bt,
    int lda, int ldb, int rowBase, int colBase, int K,
    unsigned short* As, unsigned short* Bs, f32x4 (&acc)[8][BN / 64])
{
    constexpr int NF2  = BN / 128;      // n-frags per phase (2 or 1)
    constexpr int BNH  = BN / 2;
    constexpr int ABUF = 256 * 64, AH = 128 * 64;
    constexpr int BBUF = BN * 64,  BH = BNH * 64;
    const int tid = threadIdx.x, lane = tid & 63, w = tid >> 6;
    const int wrow = (w >> 2) * 64;
    const int wcol = (w & 3) * (BN / 8);
    const int lr = lane & 15, kq = lane >> 4;
    const int niter = K >> 7;

    bf16x8 af[4][2], bq0[NF2][2], bq1[NF2][2];   // all indices compile-time (no scratch)

    // prologue: buf0 all 4 halves + b1.{A0,B0,B1}; certify buf0
    stage_half<128>(A,  lda, rowBase,       0,  As,        tid);
    stage_half<BNH>(Bt, ldb, colBase,       0,  Bs,        tid);
    stage_half<128>(A,  lda, rowBase + 128, 0,  As + AH,   tid);
    stage_half<BNH>(Bt, ldb, colBase + BNH, 0,  Bs + BH,   tid);
    stage_half<128>(A,  lda, rowBase,       64, As + ABUF, tid);
    stage_half<BNH>(Bt, ldb, colBase,       64, Bs + BBUF, tid);
    stage_half<BNH>(Bt, ldb, colBase + BNH, 64, Bs + BBUF + BH, tid);
    vmcnt_steady<BN>();
    __builtin_amdgcn_s_barrier();

    for (int I = 0; I < niter; ++I) {
        const bool nl = (I + 1 < niter);
        const int ke = I << 7;
        // ---- window0: reads buf0 (K-tile 2I) ----
        PH_RA(0, 0) PH_RB(0, 0, bq0)
        PH_MMA(0, 0, bq0, { stage_half<128>(A,  lda, rowBase + 128, ke + 64,  As + ABUF + AH, tid); }, {})     // b1.A1
        PH_RB(0, 1, bq1)
        PH_MMA(0, 1, bq1, { if (nl) stage_half<128>(A,  lda, rowBase,       ke + 128, As,      tid); }, {})    // b0'.A0
        PH_RA(0, 1)
        PH_MMA(1, 1, bq1, { if (nl) stage_half<BNH>(Bt, ldb, colBase,       ke + 128, Bs,      tid); }, {})    // b0'.B0
        PH_MMA(1, 0, bq0, { if (nl) stage_half<BNH>(Bt, ldb, colBase + BNH, ke + 128, Bs + BH, tid); },        // b0'.B1
                          { if (nl) vmcnt_steady<BN>(); else vmcnt0(); })
        // ---- window1: reads buf1 (K-tile 2I+1) ----
        PH_RA(1, 0) PH_RB(1, 0, bq0)
        PH_MMA(0, 0, bq0, { if (nl) stage_half<128>(A,  lda, rowBase + 128, ke + 128, As + AH, tid); }, {})    // b0'.A1
        PH_RB(1, 1, bq1)
        PH_MMA(0, 1, bq1, { if (nl) stage_half<128>(A,  lda, rowBase,       ke + 192, As + ABUF, tid); }, {})  // b1'.A0
        PH_RA(1, 1)
        PH_MMA(1, 1, bq1, { if (nl) stage_half<BNH>(Bt, ldb, colBase,       ke + 192, Bs + BBUF, tid); }, {})  // b1'.B0
        PH_MMA(1, 0, bq0, { if (nl) stage_half<BNH>(Bt, ldb, colBase + BNH, ke + 192, Bs + BBUF + BH, tid); }, // b1'.B1
                          { if (nl) vmcnt_steady<BN>(); })
    }
}

// ---------- prep: normalize text[1] rows -> tn, copy t1 into out, zero L & SS ----------
__global__ __launch_bounds__(256) void prep_tn_k(
    const float* __restrict__ text, unsigned short* __restrict__ tn,
    float* __restrict__ out, float* __restrict__ L, float* __restrict__ SS)
{
    const int m = blockIdx.x;
    const int t = threadIdx.x;  // 256
    const float* t1 = text + (size_t)M_SZ * D_SZ;
    float2 v = ((const float2*)(t1 + (size_t)m * D_SZ))[t];
    float s = v.x * v.x + v.y * v.y;
#pragma unroll
    for (int off = 32; off > 0; off >>= 1) s += __shfl_down(s, off);
    __shared__ float partial[4];
    if ((t & 63) == 0) partial[t >> 6] = s;
    __syncthreads();
    float norm = sqrtf(partial[0] + partial[1] + partial[2] + partial[3]);
    norm = fmaxf(norm, 1e-8f);
    const float inv = 1.f / norm;
    ushort2 pk; pk.x = f2bf(v.x * inv); pk.y = f2bf(v.y * inv);
    ((ushort2*)(tn + (size_t)m * D_SZ))[t] = pk;
#pragma unroll
    for (int b = 0; b < B_SZ; ++b)
        ((float2*)(out + ((size_t)(b * M_SZ + m)) * (2 * D_SZ) + D_SZ))[t] = v;
    if (m < 64) L[m * 256 + t] = 0.f;
    if (m < 128) SS[m * 256 + t] = 0.f;
}

// ---------- prep: transpose W (fp32 [d][e]) -> Wt (bf16 [e][d]) ----------
__global__ __launch_bounds__(256) void prep_w_k(
    const float* __restrict__ W, unsigned short* __restrict__ Wt)
{
    const int dt = blockIdx.x, et = blockIdx.y;
    const int t = threadIdx.x;
    __shared__ unsigned short tile[64][72];
    const int rr = t >> 4;
    const int cc = (t & 15) * 4;
#pragma unroll
    for (int p = 0; p < 4; ++p) {
        const int d = p * 16 + rr;
        const float4 v = *(const float4*)(W + (size_t)(dt * 64 + d) * D_SZ + et * 64 + cc);
        tile[d][cc] = f2bf(v.x); tile[d][cc + 1] = f2bf(v.y);
        tile[d][cc + 2] = f2bf(v.z); tile[d][cc + 3] = f2bf(v.w);
    }
    __syncthreads();
#pragma unroll
    for (int p = 0; p < 4; ++p) {
        const int e = p * 16 + rr;
        ushort4 pk;
        pk.x = tile[cc][e]; pk.y = tile[cc + 1][e]; pk.z = tile[cc + 2][e]; pk.w = tile[cc + 3][e];
        *(ushort4*)(Wt + (size_t)(et * 64 + e) * D_SZ + dt * 64 + cc) = pk;
    }
}

// ---------- features fp32 -> V bf16 [b*n][d] and Vt bf16 [b][d][n] ----------
__global__ __launch_bounds__(256) void convert_feat_k(
    const float* __restrict__ feat, unsigned short* __restrict__ V,
    unsigned short* __restrict__ Vt)
{
    const int nt = blockIdx.x, dt = blockIdx.y, b = blockIdx.z;
    const int t = threadIdx.x;
    __shared__ unsigned short tile[64][72];
    const int rr = t >> 4;
    const int cc = (t & 15) * 4;
#pragma unroll
    for (int p = 0; p < 4; ++p) {
        const int r = p * 16 + rr;
        const size_t grow = (size_t)(b * N_SZ + nt * 64 + r);
        const float4 v = *(const float4*)(feat + grow * D_SZ + dt * 64 + cc);
        ushort4 pk; pk.x = f2bf(v.x); pk.y = f2bf(v.y); pk.z = f2bf(v.z); pk.w = f2bf(v.w);
        *(ushort4*)(V + grow * D_SZ + dt * 64 + cc) = pk;
        tile[r][cc] = pk.x; tile[r][cc + 1] = pk.y; tile[r][cc + 2] = pk.z; tile[r][cc + 3] = pk.w;
    }
    __syncthreads();
#pragma unroll
    for (int p = 0; p < 4; ++p) {
        const int d = p * 16 + rr;
        ushort4 pk;
        pk.x = tile[cc][d]; pk.y = tile[cc + 1][d]; pk.z = tile[cc + 2][d]; pk.w = tile[cc + 3][d];
        *(ushort4*)(Vt + ((size_t)(b * D_SZ + dt * 64 + d)) * N_SZ + nt * 64 + cc) = pk;
    }
}

// ---------- gemm1 (8-phase 256x256): f1b = bf16(V @ Wt^T + bias); SS[row] += sum(f1^2) ----------
__global__ __launch_bounds__(512, 1) void gemm1_k8(
    const unsigned short* __restrict__ V, const unsigned short* __restrict__ Wt,
    const float* __restrict__ bias, unsigned short* __restrict__ f1b,
    float* __restrict__ SS)
{
    __shared__ unsigned short smem[65536];   // 128 KiB staging
    unsigned short* As = smem;
    unsigned short* Bs = smem + 32768;
    f32x4 acc[8][4];
#pragma unroll
    for (int i = 0; i < 8; ++i)
#pragma unroll
        for (int j = 0; j < 4; ++j) acc[i][j] = (f32x4){0.f, 0.f, 0.f, 0.f};

    const int lin = blockIdx.x;              // 256 blocks
    const int rowBase = (lin >> 1) * 256;    // V rows (b*n)
    const int colBase = (lin & 1) * 256;     // e cols

    mainloop8<256>(V, Wt, D_SZ, D_SZ, rowBase, colBase, D_SZ, As, Bs, acc);

    const int tid = threadIdx.x, lane = tid & 63, w = tid >> 6;
    const int wrow = (w >> 2) * 64, wcol = (w & 3) * 32;
    const int lr = lane & 15, kq = lane >> 4;

    // bias per col-frag (invariant over a)
    float bv[4];
    int cs[4];
#pragma unroll
    for (int j = 0; j < 4; ++j) {
        cs[j] = colBase + (j >> 1) * 128 + wcol + (j & 1) * 16 + lr;
        bv[j] = bias[cs[j]];
    }
#pragma unroll
    for (int a = 0; a < 8; ++a) {
        const int r0 = rowBase + (a >> 2) * 128 + wrow + (a & 3) * 16 + kq * 4;
        float s[4] = {0.f, 0.f, 0.f, 0.f};
#pragma unroll
        for (int j = 0; j < 4; ++j) {
#pragma unroll
            for (int r = 0; r < 4; ++r) {
                const float v = acc[a][j][r] + bv[j];
                f1b[(size_t)(r0 + r) * D_SZ + cs[j]] = f2bf(v);
                s[r] += v * v;
            }
        }
#pragma unroll
        for (int off = 1; off <= 8; off <<= 1)
#pragma unroll
            for (int r = 0; r < 4; ++r) s[r] += __shfl_xor(s[r], off);
        if (lr == 0) {
#pragma unroll
            for (int r = 0; r < 4; ++r) atomicAdd(&SS[r0 + r], s[r]);
        }
    }
}

// ---------- gemm2 (8-phase 256x256): sim = (f1b @ tn^T) * invnorm; E = bf16(exp); L += sums ----------
__global__ __launch_bounds__(512, 1) void gemm2_k8(
    const unsigned short* __restrict__ f1b, const unsigned short* __restrict__ tn,
    const float* __restrict__ SS, unsigned short* __restrict__ E,
    float* __restrict__ L)
{
    __shared__ unsigned short smem[65536];   // 128 KiB: staging; reused as swizzled P-tile
    __shared__ float invn[256];              // per-row 1/||f1||
    unsigned short* As = smem;               // [2][256*64]
    unsigned short* Bs = smem + 32768;       // [2][256*64]
    f32x4 acc[8][4];
#pragma unroll
    for (int i = 0; i < 8; ++i)
#pragma unroll
        for (int j = 0; j < 4; ++j) acc[i][j] = (f32x4){0.f, 0.f, 0.f, 0.f};

    const int lin = blockIdx.x;              // 1024 blocks
    const int xcd = lin & 7, slot = lin >> 3;
    const int mt = slot & 7;                 // tn col-tile (inner: tn L2-resident)
    const int rt = (slot >> 3) * 8 + xcd;    // f1 row-tile pinned per XCD
    const int rowBase = rt * 256;            // f1 rows (b*4096 + n)
    const int colBase = mt * 256;            // tn rows (m)

    mainloop8<256>(f1b, tn, D_SZ, D_SZ, rowBase, colBase, D_SZ, As, Bs, acc);

    const int tid = threadIdx.x, lane = tid & 63, w = tid >> 6;
    if (tid < 256) {
        const float ss = SS[rowBase + tid];
        invn[tid] = 1.f / fmaxf(sqrtf(ss), 1e-8f);
    }
    __syncthreads();                         // drains DMA (last iter vmcnt(0)) + publishes invn

    const int wrow = (w >> 2) * 64, wcol = (w & 3) * 32;
    const int lr = lane & 15, kq = lane >> 4;
    const int b = rowBase >> 12;
    const int nb0 = rowBase & 4095;

    // write exp(sim*invnorm) into swizzled P[m 256][n 256] (16B slot s of row m at s^(m&7))
    unsigned short* P = smem;
    float ps[4] = {0.f, 0.f, 0.f, 0.f};
#pragma unroll
    for (int a = 0; a < 8; ++a) {
        const int n0 = (a >> 2) * 128 + wrow + (a & 3) * 16 + kq * 4;   // local n
        const float4 inr = *(const float4*)(invn + n0);
#pragma unroll
        for (int j = 0; j < 4; ++j) {
            const int m = (j >> 1) * 128 + wcol + (j & 1) * 16 + lr;    // local m
            const float e0 = __expf(acc[a][j][0] * inr.x);
            const float e1 = __expf(acc[a][j][1] * inr.y);
            const float e2 = __expf(acc[a][j][2] * inr.z);
            const float e3 = __expf(acc[a][j][3] * inr.w);
            ushort4 pk; pk.x = f2bf(e0); pk.y = f2bf(e1); pk.z = f2bf(e2); pk.w = f2bf(e3);
            *(ushort4*)(P + m * 256 + (((n0 >> 3) ^ (m & 7)) * 8) + (n0 & 7)) = pk;
            ps[j] += (e0 + e1) + (e2 + e3);
        }
    }
#pragma unroll
    for (int j = 0; j < 4; ++j) {
        float p = ps[j];
        p += __shfl_down(p, 16);
        p += __shfl_down(p, 32);
        const int m = (j >> 1) * 128 + wcol + (j & 1) * 16 + lr;
        if (lane < 16) atomicAdd(&L[b * M_SZ + colBase + m], p);
    }
    __syncthreads();

    // coalesced transposed store: 32 lanes cover 512 contiguous bytes along n
    unsigned short* Eb = E + (size_t)b * M_SZ * N_SZ;
#pragma unroll
    for (int c = 0; c < 16; ++c) {
        const int rm = c * 16 + (tid >> 5);
        const int ns = tid & 31;
        bf16x8 v = *(const bf16x8*)(P + rm * 256 + ((ns ^ (rm & 7)) * 8));
        *(bf16x8*)(Eb + (size_t)(colBase + rm) * N_SZ + nb0 + ns * 8) = v;
    }
}

// ---------- gemm3 (8-phase 256x128): fm = (E @ Vt^T) / L -> out left half ----------
// XCD map: b = lin&7 (one batch per XCD -> Vt slice 4 MiB L2-fit; E-tiles
// streamed once, shared by the 4 concurrent dt-blocks of the same (b,mtile)).
__global__ __launch_bounds__(512, 1) void gemm3_k8(
    const unsigned short* __restrict__ E, const unsigned short* __restrict__ Vt,
    const float* __restrict__ L, float* __restrict__ out)
{
    __shared__ unsigned short smem[49152];   // 96 KiB: As 64K + Bs 32K
    unsigned short* As = smem;               // [2][256*64]
    unsigned short* Bs = smem + 32768;       // [2][128*64]
    f32x4 acc[8][2];
#pragma unroll
    for (int i = 0; i < 8; ++i)
#pragma unroll
        for (int j = 0; j < 2; ++j) acc[i][j] = (f32x4){0.f, 0.f, 0.f, 0.f};

    const int lin = blockIdx.x;              // 256 blocks
    const int b = lin & 7;                   // batch pinned per XCD
    const int mtile = (lin >> 3) & 7;        // E m-tile
    const int dt = lin >> 6;                 // Vt d-tile (0..3)
    const int rowBase = mtile * 256;         // m
    const int colBase = dt * 128;            // d

    const unsigned short* Ab = E + (size_t)b * M_SZ * N_SZ;
    const unsigned short* Bb = Vt + (size_t)b * D_SZ * N_SZ;
    mainloop8<128>(Ab, Bb, N_SZ, N_SZ, rowBase, colBase, N_SZ, As, Bs, acc);

    const int tid = threadIdx.x, lane = tid & 63, w = tid >> 6;
    const int wrow = (w >> 2) * 64, wcol = (w & 3) * 16;
    const int lr = lane & 15, kq = lane >> 4;

#pragma unroll
    for (int a = 0; a < 8; ++a) {
        const int r0 = rowBase + (a >> 2) * 128 + wrow + (a & 3) * 16 + kq * 4;
        float invl[4];
#pragma unroll
        for (int r = 0; r < 4; ++r) invl[r] = 1.f / L[b * M_SZ + r0 + r];
#pragma unroll
        for (int j = 0; j < 2; ++j) {
            const int d = colBase + j * 64 + wcol + lr;
#pragma unroll
            for (int r = 0; r < 4; ++r)
                out[((size_t)(b * M_SZ + r0 + r)) * (2 * D_SZ) + d] = acc[a][j][r] * invl[r];
        }
    }
}

extern "C" void kernel_launch(void* const* d_in, const int* in_sizes, int n_in,
                              void* d_out, int out_size, void* d_ws, size_t ws_size,
                              hipStream_t stream) {
    const float* features = (const float*)d_in[0];   // [8, 4096, 512]
    const float* text     = (const float*)d_in[1];   // [2, 2048, 512]
    const float* W        = (const float*)d_in[2];   // [512, 512]
    const float* bias     = (const float*)d_in[3];   // [512]
    float* out = (float*)d_out;                      // [8, 2048, 1024]
    char* ws = (char*)d_ws;

    // workspace layout (bytes)
    unsigned short* f1b = (unsigned short*)(ws + 0);            // 32 MiB (lives through gemm2)
    unsigned short* tn  = (unsigned short*)(ws + 33554432);     //  2 MiB
    unsigned short* Wt  = (unsigned short*)(ws + 35651584);     // .5 MiB
    unsigned short* V   = (unsigned short*)(ws + 36175872);     // 32 MiB
    unsigned short* Vt  = (unsigned short*)(ws + 69730304);     // 32 MiB
    float*          L   = (float*)(ws + 103284736);             // 64 KiB
    float*          SS  = (float*)(ws + 103350272);             // 128 KiB
    unsigned short* E   = (unsigned short*)(ws + 103481344);    // 128 MiB

    hipLaunchKernelGGL(prep_tn_k, dim3(M_SZ), dim3(256), 0, stream, text, tn, out, L, SS);
    hipLaunchKernelGGL(prep_w_k, dim3(8, 8), dim3(256), 0, stream, W, Wt);
    hipLaunchKernelGGL(convert_feat_k, dim3(64, 8, 8), dim3(256), 0, stream, features, V, Vt);
    hipLaunchKernelGGL(gemm1_k8, dim3(256), dim3(512), 0, stream, V, Wt, bias, f1b, SS);
    hipLaunchKernelGGL(gemm2_k8, dim3(1024), dim3(512), 0, stream, f1b, tn, SS, E, L);
    hipLaunchKernelGGL(gemm3_k8, dim3(256), dim3(512), 0, stream, E, Vt, L, out);
}